// Round 10
// baseline (351.364 us; speedup 1.0000x reference)
//
#include <hip/hip_runtime.h>
#include <hip/hip_fp16.h>
#include <math.h>

// GCN forward, reordered per-layer as x_{l} = relu((A x_{l-1}) @ W_l + b_l)
// (valid since A(xW) == (Ax)W). Then global max pool -> dot Wr.
//
// h stored fp16. Layers 2-4 are ONE fused kernel each (gmm64): gather the
// block's 64 node-rows straight into the GEMM's LDS x-tile (group-per-node,
// 8 lanes x 16B, no cross-lane reduce), then LDS-tiled vector GEMM.
// Layer 4 additionally fuses the global max-pool into the epilogue.

__global__ void init_kernel(int* counts, float* pooled, int N) {
    int i = blockIdx.x * blockDim.x + threadIdx.x;
    if (i < N) counts[i] = 0;
    if (i < 64) pooled[i] = 0.0f;  // relu >= 0 so 0-bits is max identity
}

// pass 1: reserve a slot per edge within its dst row. 800k atomics total.
__global__ void count_slot_kernel(const int* __restrict__ dst, int* counts, int* eslot, int E) {
    int e = blockIdx.x * blockDim.x + threadIdx.x;
    if (e >= E) return;
    eslot[e] = atomicAdd(&counts[dst[e]], 1);
}

// ---- two-level exclusive scan of counts -> rowptr ----
__global__ void scan1_kernel(const int* __restrict__ counts, int* bsums, int N) {
    __shared__ int s[256];
    int t = threadIdx.x, i = blockIdx.x * 256 + t;
    s[t] = (i < N) ? counts[i] : 0;
    __syncthreads();
    for (int o = 128; o > 0; o >>= 1) {
        if (t < o) s[t] += s[t + o];
        __syncthreads();
    }
    if (t == 0) bsums[blockIdx.x] = s[0];
}

__global__ void scan2_kernel(int* bsums, int nb) {  // nb <= 512
    __shared__ int s[512];
    int t = threadIdx.x;
    int v = (t < nb) ? bsums[t] : 0;
    s[t] = v; __syncthreads();
    for (int o = 1; o < 512; o <<= 1) {
        int x = (t >= o) ? s[t - o] : 0;
        __syncthreads();
        s[t] += x;
        __syncthreads();
    }
    if (t < nb) bsums[t] = s[t] - v;  // exclusive
}

__global__ void scan3_kernel(const int* __restrict__ counts, const int* __restrict__ bsums,
                             int* rowptr, int N) {
    __shared__ int s[256];
    int t = threadIdx.x, i = blockIdx.x * 256 + t;
    int v = (i < N) ? counts[i] : 0;
    s[t] = v; __syncthreads();
    for (int o = 1; o < 256; o <<= 1) {
        int x = (t >= o) ? s[t - o] : 0;
        __syncthreads();
        s[t] += x;
        __syncthreads();
    }
    if (i <= N) rowptr[i] = bsums[blockIdx.x] + s[t] - v;  // rowptr[N] == E
}

// pass 2: atomic-free CSR fill using reserved slots.
__global__ void fill2_kernel(const int* __restrict__ src, const int* __restrict__ dst,
                             const float* __restrict__ w, const int* __restrict__ rowptr,
                             const int* __restrict__ eslot, int* colsrc, float* wcsr, int E) {
    int e = blockIdx.x * blockDim.x + threadIdx.x;
    if (e >= E) return;
    int p = rowptr[dst[e]] + eslot[e];
    colsrc[p] = src[e];
    wcsr[p] = w[e];
}

// deg[i] = 1 + sum(wcsr row) (self loop), dinv = 1/sqrt(deg). Coalesced, no atomics.
__global__ void degdinv_kernel(const float* __restrict__ wcsr, const int* __restrict__ rowptr,
                               float* dinv, int N) {
    int i = blockIdx.x * blockDim.x + threadIdx.x;
    if (i >= N) return;
    float d = 1.0f;
    int jb = rowptr[i], je = rowptr[i + 1];
    for (int j = jb; j < je; ++j) d += wcsr[j];
    dinv[i] = 1.0f / sqrtf(d);
}

// in-place: wcsr[j] <- dinv[colsrc[j]] * wcsr[j] * dinv[i]
__global__ void norm_kernel(const int* __restrict__ rowptr, const int* __restrict__ colsrc,
                            const float* __restrict__ dinv, float* wcsr, int N) {
    int i = blockIdx.x * blockDim.x + threadIdx.x;
    if (i >= N) return;
    float dn = dinv[i];
    int jb = rowptr[i], je = rowptr[i + 1];
    for (int j = jb; j < je; ++j)
        wcsr[j] = dinv[colsrc[j]] * wcsr[j] * dn;
}

// 6-wide gather over raw input features: g[i] = dinv[i]^2*x[i] + sum norm*x[src].
__global__ void gather6_kernel(const float* __restrict__ x, const int* __restrict__ rowptr,
                               const int* __restrict__ colsrc, const float* __restrict__ normcsr,
                               const float* __restrict__ dinv, float* __restrict__ g, int N) {
    int i = blockIdx.x * blockDim.x + threadIdx.x;
    if (i >= N) return;
    float dn = dinv[i];
    float sc = dn * dn;
    float acc[6];
    {
        const float2* xr = (const float2*)(x + (size_t)i * 6);
        float2 a = xr[0], bv = xr[1], c = xr[2];
        acc[0] = sc * a.x; acc[1] = sc * a.y; acc[2] = sc * bv.x;
        acc[3] = sc * bv.y; acc[4] = sc * c.x; acc[5] = sc * c.y;
    }
    int jb = rowptr[i], je = rowptr[i + 1];
    for (int j = jb; j < je; ++j) {
        int s = colsrc[j];
        float nm = normcsr[j];
        const float2* xr = (const float2*)(x + (size_t)s * 6);
        float2 a = xr[0], bv = xr[1], c = xr[2];
        acc[0] = fmaf(nm, a.x, acc[0]); acc[1] = fmaf(nm, a.y, acc[1]);
        acc[2] = fmaf(nm, bv.x, acc[2]); acc[3] = fmaf(nm, bv.y, acc[3]);
        acc[4] = fmaf(nm, c.x, acc[4]); acc[5] = fmaf(nm, c.y, acc[5]);
    }
#pragma unroll
    for (int f = 0; f < 6; ++f) g[(size_t)i * 6 + f] = acc[f];
}

// h[n*64+c] = relu(xin[n] @ W[:,c] + b[c]) -> fp16, 6->64. Thread per (node,ch).
__global__ void __launch_bounds__(256)
mm6_kernel(const float* __restrict__ xin, const float* __restrict__ W,
           const float* __restrict__ b, __half* __restrict__ h, int N) {
    long idx = (long)blockIdx.x * blockDim.x + threadIdx.x;  // node*64 + ch
    if (idx >= (long)N * 64) return;
    long n = idx >> 6;
    int c = (int)(idx & 63);
    const float* xr = xin + n * 6;
    float a = b[c];
    a = fmaf(xr[0], W[0 * 64 + c], a);
    a = fmaf(xr[1], W[1 * 64 + c], a);
    a = fmaf(xr[2], W[2 * 64 + c], a);
    a = fmaf(xr[3], W[3 * 64 + c], a);
    a = fmaf(xr[4], W[4 * 64 + c], a);
    a = fmaf(xr[5], W[5 * 64 + c], a);
    h[idx] = __float2half(fmaxf(a, 0.0f));
}

// Fused gather + GEMM (+ optional max-pool) for one 64->64 GCN layer.
// Phase 1 (gather): 32 groups x 8 lanes; group owns one node, lane owns a
//   fixed 16B slot of the 128B fp16 row -> no cross-lane reduce; results go
//   straight into the LDS x-tile (fp32). Two 32-node halves per block.
// Phase 2 (GEMM): thread (ty,tx) = 4 nodes x 4 ch, 4x float4 acc.
// FUSE_POOL: epilogue computes relu+bias then block max-reduce + atomicMax,
//   h_out is not written.
template<bool FUSE_POOL>
__global__ void __launch_bounds__(256)
__attribute__((amdgpu_waves_per_eu(2, 4)))
gmm64_kernel(const __half* __restrict__ h_in, const int* __restrict__ rowptr,
             const int* __restrict__ colsrc, const float* __restrict__ normcsr,
             const float* __restrict__ dinv,
             const float* __restrict__ W, const float* __restrict__ b,
             __half* __restrict__ h_out, float* pooled, int N) {
    __shared__ float xl[64 * 68];
    __shared__ float Wt[64 * 68];
    const int tid = threadIdx.x;
    const long nb = (long)blockIdx.x * 64;

    // stage W[k][c] (row-major, pad 68)
#pragma unroll
    for (int r = 0; r < 4; ++r) {
        int q = tid + 256 * r;          // float4 index 0..1023
        int row = q >> 4, c4 = q & 15;
        ((float4*)&Wt[row * 68 + c4 * 4])[0] = ((const float4*)W)[q];
    }

    // ---- gather phase: group-per-node ----
    const int grp = tid >> 3;   // 0..31
    const int l8 = tid & 7;     // 16B slot
#pragma unroll
    for (int half = 0; half < 2; ++half) {
        int row = half * 32 + grp;
        long node = nb + row;
        float4 accA = {0.f, 0.f, 0.f, 0.f};
        float4 accB = {0.f, 0.f, 0.f, 0.f};
        if (node < N) {
            float dn = dinv[node];
            float sc = dn * dn;
            uint4 r = ((const uint4*)(h_in + node * 64))[l8];
            __half2 p0 = *(__half2*)&r.x, p1 = *(__half2*)&r.y;
            __half2 p2 = *(__half2*)&r.z, p3 = *(__half2*)&r.w;
            float2 f0 = __half22float2(p0), f1 = __half22float2(p1);
            float2 f2 = __half22float2(p2), f3 = __half22float2(p3);
            accA.x = sc * f0.x; accA.y = sc * f0.y; accA.z = sc * f1.x; accA.w = sc * f1.y;
            accB.x = sc * f2.x; accB.y = sc * f2.y; accB.z = sc * f3.x; accB.w = sc * f3.y;
            int jb = rowptr[node], je = rowptr[node + 1];
            for (int j = jb; j < je; ++j) {
                int s = colsrc[j];
                float nm = normcsr[j];
                uint4 rr = ((const uint4*)(h_in + (size_t)s * 64))[l8];
                __half2 q0 = *(__half2*)&rr.x, q1 = *(__half2*)&rr.y;
                __half2 q2 = *(__half2*)&rr.z, q3 = *(__half2*)&rr.w;
                float2 g0 = __half22float2(q0), g1 = __half22float2(q1);
                float2 g2 = __half22float2(q2), g3 = __half22float2(q3);
                accA.x = fmaf(nm, g0.x, accA.x); accA.y = fmaf(nm, g0.y, accA.y);
                accA.z = fmaf(nm, g1.x, accA.z); accA.w = fmaf(nm, g1.y, accA.w);
                accB.x = fmaf(nm, g2.x, accB.x); accB.y = fmaf(nm, g2.y, accB.y);
                accB.z = fmaf(nm, g3.x, accB.z); accB.w = fmaf(nm, g3.y, accB.w);
            }
        }
        float* dstp = &xl[row * 68 + l8 * 8];
        ((float4*)dstp)[0] = accA;
        ((float4*)dstp)[1] = accB;
    }
    __syncthreads();

    // ---- GEMM phase ----
    const int tx = tid & 15;   // channel group: ch = tx*4..+3
    const int ty = tid >> 4;   // node group:    n = ty*4..+3

    float4 acc0 = {0,0,0,0}, acc1 = {0,0,0,0}, acc2 = {0,0,0,0}, acc3 = {0,0,0,0};
#pragma unroll 4
    for (int kc = 0; kc < 16; ++kc) {
        float4 w0 = *(const float4*)&Wt[(kc * 4 + 0) * 68 + tx * 4];
        float4 w1 = *(const float4*)&Wt[(kc * 4 + 1) * 68 + tx * 4];
        float4 w2 = *(const float4*)&Wt[(kc * 4 + 2) * 68 + tx * 4];
        float4 w3 = *(const float4*)&Wt[(kc * 4 + 3) * 68 + tx * 4];
        float4 x0 = *(const float4*)&xl[(ty * 4 + 0) * 68 + kc * 4];
        float4 x1 = *(const float4*)&xl[(ty * 4 + 1) * 68 + kc * 4];
        float4 x2 = *(const float4*)&xl[(ty * 4 + 2) * 68 + kc * 4];
        float4 x3 = *(const float4*)&xl[(ty * 4 + 3) * 68 + kc * 4];
#define MMSTEP(A, X) \
        A.x = fmaf(X.x, w0.x, A.x); A.y = fmaf(X.x, w0.y, A.y); A.z = fmaf(X.x, w0.z, A.z); A.w = fmaf(X.x, w0.w, A.w); \
        A.x = fmaf(X.y, w1.x, A.x); A.y = fmaf(X.y, w1.y, A.y); A.z = fmaf(X.y, w1.z, A.z); A.w = fmaf(X.y, w1.w, A.w); \
        A.x = fmaf(X.z, w2.x, A.x); A.y = fmaf(X.z, w2.y, A.y); A.z = fmaf(X.z, w2.z, A.z); A.w = fmaf(X.z, w2.w, A.w); \
        A.x = fmaf(X.w, w3.x, A.x); A.y = fmaf(X.w, w3.y, A.y); A.z = fmaf(X.w, w3.z, A.z); A.w = fmaf(X.w, w3.w, A.w);
        MMSTEP(acc0, x0) MMSTEP(acc1, x1) MMSTEP(acc2, x2) MMSTEP(acc3, x3)
#undef MMSTEP
    }

    float4 vb = ((const float4*)b)[tx];
    if (!FUSE_POOL) {
#define MMOUT(A, I) { \
        long n = nb + ty * 4 + I; \
        if (n < N) { \
            float o0 = fmaxf(A.x + vb.x, 0.f), o1 = fmaxf(A.y + vb.y, 0.f); \
            float o2 = fmaxf(A.z + vb.z, 0.f), o3 = fmaxf(A.w + vb.w, 0.f); \
            __half2 p0 = __floats2half2_rn(o0, o1), p1 = __floats2half2_rn(o2, o3); \
            uint2 pk; pk.x = *(unsigned int*)&p0; pk.y = *(unsigned int*)&p1; \
            ((uint2*)(h_out + n * 64))[tx] = pk; \
        } }
        MMOUT(acc0, 0) MMOUT(acc1, 1) MMOUT(acc2, 2) MMOUT(acc3, 3)
#undef MMOUT
    } else {
        float4 m = {0.f, 0.f, 0.f, 0.f};
#define MMMAX(A, I) { \
        long n = nb + ty * 4 + I; \
        if (n < N) { \
            m.x = fmaxf(m.x, A.x + vb.x); m.y = fmaxf(m.y, A.y + vb.y); \
            m.z = fmaxf(m.z, A.z + vb.z); m.w = fmaxf(m.w, A.w + vb.w); \
        } }
        MMMAX(acc0, 0) MMMAX(acc1, 1) MMMAX(acc2, 2) MMMAX(acc3, 3)
#undef MMMAX
        // m already >= 0 baseline; relu(v) = max(v,0) folded by the 0-init.
        __syncthreads();                        // done reading xl
        ((float4*)xl)[ty * 16 + tx] = m;        // xl as [16 ty][16 tx] float4
        __syncthreads();
#pragma unroll
        for (int off = 8; off > 0; off >>= 1) {
            if (ty < off) {
                float4 a = ((float4*)xl)[ty * 16 + tx];
                float4 c = ((float4*)xl)[(ty + off) * 16 + tx];
                a.x = fmaxf(a.x, c.x); a.y = fmaxf(a.y, c.y);
                a.z = fmaxf(a.z, c.z); a.w = fmaxf(a.w, c.w);
                ((float4*)xl)[ty * 16 + tx] = a;
            }
            __syncthreads();
        }
        if (ty == 0) {
            float4 m0 = ((float4*)xl)[tx];
            atomicMax((unsigned int*)&pooled[tx * 4 + 0], __float_as_uint(m0.x));
            atomicMax((unsigned int*)&pooled[tx * 4 + 1], __float_as_uint(m0.y));
            atomicMax((unsigned int*)&pooled[tx * 4 + 2], __float_as_uint(m0.z));
            atomicMax((unsigned int*)&pooled[tx * 4 + 3], __float_as_uint(m0.w));
        }
    }
}

__global__ void out_kernel(const float* __restrict__ pooled, const float* __restrict__ Wr,
                           const float* __restrict__ br, float* out) {
    int lane = threadIdx.x;
    float v = pooled[lane] * Wr[lane];
    for (int o = 32; o > 0; o >>= 1) v += __shfl_xor(v, o);
    if (lane == 0) out[0] = v + br[0];
}

extern "C" void kernel_launch(void* const* d_in, const int* in_sizes, int n_in,
                              void* d_out, int out_size, void* d_ws, size_t ws_size,
                              hipStream_t stream) {
    const float* vf = (const float*)d_in[0];
    const int* edges = (const int*)d_in[1];
    const float* w = (const float*)d_in[2];
    const float* W1 = (const float*)d_in[3];  const float* b1 = (const float*)d_in[4];
    const float* W2 = (const float*)d_in[5];  const float* b2 = (const float*)d_in[6];
    const float* W3 = (const float*)d_in[7];  const float* b3 = (const float*)d_in[8];
    const float* W4 = (const float*)d_in[9];  const float* b4 = (const float*)d_in[10];
    const float* Wr = (const float*)d_in[11]; const float* br = (const float*)d_in[12];
    float* out = (float*)d_out;

    const int FIN = 6;
    const int N = in_sizes[0] / FIN;   // 100000
    const int E = in_sizes[2];         // 800000
    const int* src = edges;
    const int* dst = edges + E;

    char* p = (char*)d_ws;
    float*  dinv    = (float*)p;   p += (size_t)N * 4;
    int*    rowptr  = (int*)p;     p += (size_t)(N + 1) * 4;
    int*    counts  = (int*)p;     p += (size_t)N * 4;
    int*    eslot   = (int*)p;     p += (size_t)E * 4;
    int*    colsrc  = (int*)p;     p += (size_t)E * 4;
    float*  wcsr    = (float*)p;   p += (size_t)E * 4;   // becomes normcsr in-place
    float*  g6      = (float*)p;   p += (size_t)N * 6 * 4;
    __half* hA      = (__half*)p;  p += (size_t)N * 64 * 2;
    __half* hB      = (__half*)p;  p += (size_t)N * 64 * 2;
    float*  pooled  = (float*)p;   p += 64 * 4;
    int*    bsums   = (int*)p;     p += 512 * 4;

    const int nbN = (N + 255) / 256;          // 391
    const int nbE = (E + 255) / 256;          // 3125
    const int nbG = (N + 63) / 64;            // fused layer blocks (64 nodes each)
    const int nbM6 = (int)(((long)N * 64 + 255) / 256);  // mm6: thread per (node,ch)

    init_kernel<<<nbN, 256, 0, stream>>>(counts, pooled, N);
    count_slot_kernel<<<nbE, 256, 0, stream>>>(dst, counts, eslot, E);
    scan1_kernel<<<nbN, 256, 0, stream>>>(counts, bsums, N);
    scan2_kernel<<<1, 512, 0, stream>>>(bsums, nbN);
    scan3_kernel<<<nbN, 256, 0, stream>>>(counts, bsums, rowptr, N);
    fill2_kernel<<<nbE, 256, 0, stream>>>(src, dst, w, rowptr, eslot, colsrc, wcsr, E);
    degdinv_kernel<<<nbN, 256, 0, stream>>>(wcsr, rowptr, dinv, N);
    norm_kernel<<<nbN, 256, 0, stream>>>(rowptr, colsrc, dinv, wcsr, N);

    // layer 1: gather 6-wide, then mm 6->64 (+bias+relu) -> fp16 hA
    gather6_kernel<<<nbN, 256, 0, stream>>>(vf, rowptr, colsrc, wcsr, dinv, g6, N);
    mm6_kernel<<<nbM6, 256, 0, stream>>>(g6, W1, b1, hA, N);
    // layers 2-4: fused gather+GEMM (layer 4 also fuses max-pool)
    gmm64_kernel<false><<<nbG, 256, 0, stream>>>(hA, rowptr, colsrc, wcsr, dinv,
                                                 W2, b2, hB, nullptr, N);
    gmm64_kernel<false><<<nbG, 256, 0, stream>>>(hB, rowptr, colsrc, wcsr, dinv,
                                                 W3, b3, hA, nullptr, N);
    gmm64_kernel<true><<<nbG, 256, 0, stream>>>(hA, rowptr, colsrc, wcsr, dinv,
                                                W4, b4, nullptr, pooled, N);

    out_kernel<<<1, 64, 0, stream>>>(pooled, Wr, br, out);
}

// Round 11
// 340.360 us; speedup vs baseline: 1.0323x; 1.0323x over previous
//
#include <hip/hip_runtime.h>
#include <hip/hip_fp16.h>
#include <math.h>

// GCN forward, reordered per-layer as x_{l} = relu((A x_{l-1}) @ W_l + b_l)
// (valid since A(xW) == (Ax)W). Then global max pool -> dot Wr.
//
// Split gather/mm per layer (fusion measured worse: serial edge walks +
// LDS-capped occupancy). h AND agg stored fp16 (random-gather + stream bytes
// halved); CSR packed as int2{src, w_bits} -> one 8B load per edge.
// Layer 4's mm fuses the global max-pool epilogue.

__global__ void init_kernel(int* counts, float* pooled, int N) {
    int i = blockIdx.x * blockDim.x + threadIdx.x;
    if (i < N) counts[i] = 0;
    if (i < 64) pooled[i] = 0.0f;  // relu >= 0 so 0-bits is max identity
}

// pass 1: reserve a slot per edge within its dst row. 800k atomics total.
__global__ void count_slot_kernel(const int* __restrict__ dst, int* counts, int* eslot, int E) {
    int e = blockIdx.x * blockDim.x + threadIdx.x;
    if (e >= E) return;
    eslot[e] = atomicAdd(&counts[dst[e]], 1);
}

// ---- two-level exclusive scan of counts -> rowptr ----
__global__ void scan1_kernel(const int* __restrict__ counts, int* bsums, int N) {
    __shared__ int s[256];
    int t = threadIdx.x, i = blockIdx.x * 256 + t;
    s[t] = (i < N) ? counts[i] : 0;
    __syncthreads();
    for (int o = 128; o > 0; o >>= 1) {
        if (t < o) s[t] += s[t + o];
        __syncthreads();
    }
    if (t == 0) bsums[blockIdx.x] = s[0];
}

__global__ void scan2_kernel(int* bsums, int nb) {  // nb <= 512
    __shared__ int s[512];
    int t = threadIdx.x;
    int v = (t < nb) ? bsums[t] : 0;
    s[t] = v; __syncthreads();
    for (int o = 1; o < 512; o <<= 1) {
        int x = (t >= o) ? s[t - o] : 0;
        __syncthreads();
        s[t] += x;
        __syncthreads();
    }
    if (t < nb) bsums[t] = s[t] - v;  // exclusive
}

__global__ void scan3_kernel(const int* __restrict__ counts, const int* __restrict__ bsums,
                             int* rowptr, int N) {
    __shared__ int s[256];
    int t = threadIdx.x, i = blockIdx.x * 256 + t;
    int v = (i < N) ? counts[i] : 0;
    s[t] = v; __syncthreads();
    for (int o = 1; o < 256; o <<= 1) {
        int x = (t >= o) ? s[t - o] : 0;
        __syncthreads();
        s[t] += x;
        __syncthreads();
    }
    if (i <= N) rowptr[i] = bsums[blockIdx.x] + s[t] - v;  // rowptr[N] == E
}

// pass 2: atomic-free CSR fill using reserved slots. Packed int2{src, w_bits}.
__global__ void fill2_kernel(const int* __restrict__ src, const int* __restrict__ dst,
                             const float* __restrict__ w, const int* __restrict__ rowptr,
                             const int* __restrict__ eslot, int2* __restrict__ csr, int E) {
    int e = blockIdx.x * blockDim.x + threadIdx.x;
    if (e >= E) return;
    int p = rowptr[dst[e]] + eslot[e];
    csr[p] = make_int2(src[e], __float_as_int(w[e]));
}

// deg[i] = 1 + sum(w row) (self loop), dinv = 1/sqrt(deg). Coalesced, no atomics.
__global__ void degdinv_kernel(const int2* __restrict__ csr, const int* __restrict__ rowptr,
                               float* dinv, int N) {
    int i = blockIdx.x * blockDim.x + threadIdx.x;
    if (i >= N) return;
    float d = 1.0f;
    int jb = rowptr[i], je = rowptr[i + 1];
    for (int j = jb; j < je; ++j) d += __int_as_float(csr[j].y);
    dinv[i] = 1.0f / sqrtf(d);
}

// in-place: csr[j].y <- dinv[src] * w * dinv[i]
__global__ void norm_kernel(const int* __restrict__ rowptr, const float* __restrict__ dinv,
                            int2* __restrict__ csr, int N) {
    int i = blockIdx.x * blockDim.x + threadIdx.x;
    if (i >= N) return;
    float dn = dinv[i];
    int jb = rowptr[i], je = rowptr[i + 1];
    for (int j = jb; j < je; ++j) {
        int2 ed = csr[j];
        csr[j] = make_int2(ed.x, __float_as_int(dinv[ed.x] * __int_as_float(ed.y) * dn));
    }
}

// 6-wide gather over raw input features: g[i] = dinv[i]^2*x[i] + sum norm*x[src].
__global__ void gather6_kernel(const float* __restrict__ x, const int* __restrict__ rowptr,
                               const int2* __restrict__ csr,
                               const float* __restrict__ dinv, float* __restrict__ g, int N) {
    int i = blockIdx.x * blockDim.x + threadIdx.x;
    if (i >= N) return;
    float dn = dinv[i];
    float sc = dn * dn;
    float acc[6];
    {
        const float2* xr = (const float2*)(x + (size_t)i * 6);
        float2 a = xr[0], bv = xr[1], c = xr[2];
        acc[0] = sc * a.x; acc[1] = sc * a.y; acc[2] = sc * bv.x;
        acc[3] = sc * bv.y; acc[4] = sc * c.x; acc[5] = sc * c.y;
    }
    int jb = rowptr[i], je = rowptr[i + 1];
    for (int j = jb; j < je; ++j) {
        int2 ed = csr[j];
        float nm = __int_as_float(ed.y);
        const float2* xr = (const float2*)(x + (size_t)ed.x * 6);
        float2 a = xr[0], bv = xr[1], c = xr[2];
        acc[0] = fmaf(nm, a.x, acc[0]); acc[1] = fmaf(nm, a.y, acc[1]);
        acc[2] = fmaf(nm, bv.x, acc[2]); acc[3] = fmaf(nm, bv.y, acc[3]);
        acc[4] = fmaf(nm, c.x, acc[4]); acc[5] = fmaf(nm, c.y, acc[5]);
    }
#pragma unroll
    for (int f = 0; f < 6; ++f) g[(size_t)i * 6 + f] = acc[f];
}

// 64-wide gather over fp16 h: wave per node, 8 edge-groups x 8 lanes,
// uint4 (8 halves) per lane -> 8 random 128B rows in flight. fp32 accumulate,
// 3-step shfl reduce, group 0 writes the fp16 agg row (uint4).
__global__ void gather64_kernel(const __half* __restrict__ h, const int* __restrict__ rowptr,
                                const int2* __restrict__ csr,
                                const float* __restrict__ dinv, __half* __restrict__ agg, int N) {
    int wid = blockIdx.x * (blockDim.x >> 6) + (threadIdx.x >> 6);
    if (wid >= N) return;
    int lane = threadIdx.x & 63;
    int g = lane >> 3;      // edge group 0..7
    int l8 = lane & 7;      // 16B slot within 128B row
    float4 accA = {0.f, 0.f, 0.f, 0.f};
    float4 accB = {0.f, 0.f, 0.f, 0.f};
    if (g == 0) {
        float dn = dinv[wid];
        float sc = dn * dn;
        uint4 r = ((const uint4*)(h + (size_t)wid * 64))[l8];
        __half2 p0 = *(__half2*)&r.x, p1 = *(__half2*)&r.y;
        __half2 p2 = *(__half2*)&r.z, p3 = *(__half2*)&r.w;
        float2 f0 = __half22float2(p0), f1 = __half22float2(p1);
        float2 f2 = __half22float2(p2), f3 = __half22float2(p3);
        accA.x = sc * f0.x; accA.y = sc * f0.y; accA.z = sc * f1.x; accA.w = sc * f1.y;
        accB.x = sc * f2.x; accB.y = sc * f2.y; accB.z = sc * f3.x; accB.w = sc * f3.y;
    }
    int jb = rowptr[wid], je = rowptr[wid + 1];
    for (int j = jb + g; j < je; j += 8) {
        int2 ed = csr[j];
        float nm = __int_as_float(ed.y);
        uint4 r = ((const uint4*)(h + (size_t)ed.x * 64))[l8];
        __half2 p0 = *(__half2*)&r.x, p1 = *(__half2*)&r.y;
        __half2 p2 = *(__half2*)&r.z, p3 = *(__half2*)&r.w;
        float2 f0 = __half22float2(p0), f1 = __half22float2(p1);
        float2 f2 = __half22float2(p2), f3 = __half22float2(p3);
        accA.x = fmaf(nm, f0.x, accA.x); accA.y = fmaf(nm, f0.y, accA.y);
        accA.z = fmaf(nm, f1.x, accA.z); accA.w = fmaf(nm, f1.y, accA.w);
        accB.x = fmaf(nm, f2.x, accB.x); accB.y = fmaf(nm, f2.y, accB.y);
        accB.z = fmaf(nm, f3.x, accB.z); accB.w = fmaf(nm, f3.y, accB.w);
    }
#pragma unroll
    for (int o = 8; o <= 32; o <<= 1) {
        accA.x += __shfl_xor(accA.x, o);
        accA.y += __shfl_xor(accA.y, o);
        accA.z += __shfl_xor(accA.z, o);
        accA.w += __shfl_xor(accA.w, o);
        accB.x += __shfl_xor(accB.x, o);
        accB.y += __shfl_xor(accB.y, o);
        accB.z += __shfl_xor(accB.z, o);
        accB.w += __shfl_xor(accB.w, o);
    }
    if (g == 0) {
        __half2 q0 = __floats2half2_rn(accA.x, accA.y);
        __half2 q1 = __floats2half2_rn(accA.z, accA.w);
        __half2 q2 = __floats2half2_rn(accB.x, accB.y);
        __half2 q3 = __floats2half2_rn(accB.z, accB.w);
        uint4 pk;
        pk.x = *(unsigned int*)&q0; pk.y = *(unsigned int*)&q1;
        pk.z = *(unsigned int*)&q2; pk.w = *(unsigned int*)&q3;
        ((uint4*)(agg + (size_t)wid * 64))[l8] = pk;
    }
}

// h = relu(xin @ W + b), 64->64 fp16-in fp32-math. LDS-tiled vector GEMM;
// thread (ty,tx) = 4 nodes x 4 ch. FUSE_POOL: epilogue does block max-reduce
// + atomicMax into pooled instead of writing h_out.
template<bool FUSE_POOL>
__global__ void __launch_bounds__(256)
__attribute__((amdgpu_waves_per_eu(2, 4)))
mm64_kernel(const __half* __restrict__ xin, const float* __restrict__ W,
            const float* __restrict__ b, __half* __restrict__ h_out,
            float* pooled, int N) {
    __shared__ float xl[64 * 68];
    __shared__ float Wt[64 * 68];
    const int tid = threadIdx.x;
    const long nb = (long)blockIdx.x * 64;

#pragma unroll
    for (int r = 0; r < 4; ++r) {
        int q = tid + 256 * r;          // float4 index 0..1023
        int row = q >> 4, c4 = q & 15;
        ((float4*)&Wt[row * 68 + c4 * 4])[0] = ((const float4*)W)[q];
    }
#pragma unroll
    for (int r = 0; r < 2; ++r) {
        int q = tid + 256 * r;          // uint4 index 0..511 (64 rows x 8)
        int row = q >> 3, u4 = q & 7;
        long n = nb + row;
        float4 vA = {0.f, 0.f, 0.f, 0.f}, vB = {0.f, 0.f, 0.f, 0.f};
        if (n < N) {
            uint4 rr = ((const uint4*)(xin + n * 64))[u4];
            __half2 p0 = *(__half2*)&rr.x, p1 = *(__half2*)&rr.y;
            __half2 p2 = *(__half2*)&rr.z, p3 = *(__half2*)&rr.w;
            float2 f0 = __half22float2(p0), f1 = __half22float2(p1);
            float2 f2 = __half22float2(p2), f3 = __half22float2(p3);
            vA.x = f0.x; vA.y = f0.y; vA.z = f1.x; vA.w = f1.y;
            vB.x = f2.x; vB.y = f2.y; vB.z = f3.x; vB.w = f3.y;
        }
        float* dstp = &xl[row * 68 + u4 * 8];
        ((float4*)dstp)[0] = vA;
        ((float4*)dstp)[1] = vB;
    }
    __syncthreads();

    const int tx = tid & 15;   // channel group: ch = tx*4..+3
    const int ty = tid >> 4;   // node group:    n = ty*4..+3

    float4 acc0 = {0,0,0,0}, acc1 = {0,0,0,0}, acc2 = {0,0,0,0}, acc3 = {0,0,0,0};
#pragma unroll 4
    for (int kc = 0; kc < 16; ++kc) {
        float4 w0 = *(const float4*)&Wt[(kc * 4 + 0) * 68 + tx * 4];
        float4 w1 = *(const float4*)&Wt[(kc * 4 + 1) * 68 + tx * 4];
        float4 w2 = *(const float4*)&Wt[(kc * 4 + 2) * 68 + tx * 4];
        float4 w3 = *(const float4*)&Wt[(kc * 4 + 3) * 68 + tx * 4];
        float4 x0 = *(const float4*)&xl[(ty * 4 + 0) * 68 + kc * 4];
        float4 x1 = *(const float4*)&xl[(ty * 4 + 1) * 68 + kc * 4];
        float4 x2 = *(const float4*)&xl[(ty * 4 + 2) * 68 + kc * 4];
        float4 x3 = *(const float4*)&xl[(ty * 4 + 3) * 68 + kc * 4];
#define MMSTEP(A, X) \
        A.x = fmaf(X.x, w0.x, A.x); A.y = fmaf(X.x, w0.y, A.y); A.z = fmaf(X.x, w0.z, A.z); A.w = fmaf(X.x, w0.w, A.w); \
        A.x = fmaf(X.y, w1.x, A.x); A.y = fmaf(X.y, w1.y, A.y); A.z = fmaf(X.y, w1.z, A.z); A.w = fmaf(X.y, w1.w, A.w); \
        A.x = fmaf(X.z, w2.x, A.x); A.y = fmaf(X.z, w2.y, A.y); A.z = fmaf(X.z, w2.z, A.z); A.w = fmaf(X.z, w2.w, A.w); \
        A.x = fmaf(X.w, w3.x, A.x); A.y = fmaf(X.w, w3.y, A.y); A.z = fmaf(X.w, w3.z, A.z); A.w = fmaf(X.w, w3.w, A.w);
        MMSTEP(acc0, x0) MMSTEP(acc1, x1) MMSTEP(acc2, x2) MMSTEP(acc3, x3)
#undef MMSTEP
    }

    float4 vb = ((const float4*)b)[tx];
    if (!FUSE_POOL) {
#define MMOUT(A, I) { \
        long n = nb + ty * 4 + I; \
        if (n < N) { \
            float o0 = fmaxf(A.x + vb.x, 0.f), o1 = fmaxf(A.y + vb.y, 0.f); \
            float o2 = fmaxf(A.z + vb.z, 0.f), o3 = fmaxf(A.w + vb.w, 0.f); \
            __half2 p0 = __floats2half2_rn(o0, o1), p1 = __floats2half2_rn(o2, o3); \
            uint2 pk; pk.x = *(unsigned int*)&p0; pk.y = *(unsigned int*)&p1; \
            ((uint2*)(h_out + n * 64))[tx] = pk; \
        } }
        MMOUT(acc0, 0) MMOUT(acc1, 1) MMOUT(acc2, 2) MMOUT(acc3, 3)
#undef MMOUT
    } else {
        float4 m = {0.f, 0.f, 0.f, 0.f};
#define MMMAX(A, I) { \
        long n = nb + ty * 4 + I; \
        if (n < N) { \
            m.x = fmaxf(m.x, A.x + vb.x); m.y = fmaxf(m.y, A.y + vb.y); \
            m.z = fmaxf(m.z, A.z + vb.z); m.w = fmaxf(m.w, A.w + vb.w); \
        } }
        MMMAX(acc0, 0) MMMAX(acc1, 1) MMMAX(acc2, 2) MMMAX(acc3, 3)
#undef MMMAX
        __syncthreads();                        // done reading xl
        ((float4*)xl)[ty * 16 + tx] = m;        // xl as [16 ty][16 tx] float4
        __syncthreads();
#pragma unroll
        for (int off = 8; off > 0; off >>= 1) {
            if (ty < off) {
                float4 a = ((float4*)xl)[ty * 16 + tx];
                float4 c = ((float4*)xl)[(ty + off) * 16 + tx];
                a.x = fmaxf(a.x, c.x); a.y = fmaxf(a.y, c.y);
                a.z = fmaxf(a.z, c.z); a.w = fmaxf(a.w, c.w);
                ((float4*)xl)[ty * 16 + tx] = a;
            }
            __syncthreads();
        }
        if (ty == 0) {
            float4 m0 = ((float4*)xl)[tx];
            atomicMax((unsigned int*)&pooled[tx * 4 + 0], __float_as_uint(m0.x));
            atomicMax((unsigned int*)&pooled[tx * 4 + 1], __float_as_uint(m0.y));
            atomicMax((unsigned int*)&pooled[tx * 4 + 2], __float_as_uint(m0.z));
            atomicMax((unsigned int*)&pooled[tx * 4 + 3], __float_as_uint(m0.w));
        }
    }
}

// h[n*64+c] = relu(xin[n] @ W[:,c] + b[c]) -> fp16, 6->64. Thread per (node,ch).
__global__ void __launch_bounds__(256)
mm6_kernel(const float* __restrict__ xin, const float* __restrict__ W,
           const float* __restrict__ b, __half* __restrict__ h, int N) {
    long idx = (long)blockIdx.x * blockDim.x + threadIdx.x;  // node*64 + ch
    if (idx >= (long)N * 64) return;
    long n = idx >> 6;
    int c = (int)(idx & 63);
    const float* xr = xin + n * 6;
    float a = b[c];
    a = fmaf(xr[0], W[0 * 64 + c], a);
    a = fmaf(xr[1], W[1 * 64 + c], a);
    a = fmaf(xr[2], W[2 * 64 + c], a);
    a = fmaf(xr[3], W[3 * 64 + c], a);
    a = fmaf(xr[4], W[4 * 64 + c], a);
    a = fmaf(xr[5], W[5 * 64 + c], a);
    h[idx] = __float2half(fmaxf(a, 0.0f));
}

__global__ void out_kernel(const float* __restrict__ pooled, const float* __restrict__ Wr,
                           const float* __restrict__ br, float* out) {
    int lane = threadIdx.x;
    float v = pooled[lane] * Wr[lane];
    for (int o = 32; o > 0; o >>= 1) v += __shfl_xor(v, o);
    if (lane == 0) out[0] = v + br[0];
}

extern "C" void kernel_launch(void* const* d_in, const int* in_sizes, int n_in,
                              void* d_out, int out_size, void* d_ws, size_t ws_size,
                              hipStream_t stream) {
    const float* vf = (const float*)d_in[0];
    const int* edges = (const int*)d_in[1];
    const float* w = (const float*)d_in[2];
    const float* W1 = (const float*)d_in[3];  const float* b1 = (const float*)d_in[4];
    const float* W2 = (const float*)d_in[5];  const float* b2 = (const float*)d_in[6];
    const float* W3 = (const float*)d_in[7];  const float* b3 = (const float*)d_in[8];
    const float* W4 = (const float*)d_in[9];  const float* b4 = (const float*)d_in[10];
    const float* Wr = (const float*)d_in[11]; const float* br = (const float*)d_in[12];
    float* out = (float*)d_out;

    const int FIN = 6;
    const int N = in_sizes[0] / FIN;   // 100000
    const int E = in_sizes[2];         // 800000
    const int* src = edges;
    const int* dst = edges + E;

    char* p = (char*)d_ws;
    float*  dinv    = (float*)p;   p += (size_t)N * 4;
    int*    rowptr  = (int*)p;     p += (size_t)(N + 1) * 4;
    int*    counts  = (int*)p;     p += (size_t)N * 4;
    int*    eslot   = (int*)p;     p += (size_t)E * 4;
    int2*   csr     = (int2*)p;    p += (size_t)E * 8;   // {src, w/norm bits}
    float*  g6      = (float*)p;   p += (size_t)N * 6 * 4;
    __half* hA      = (__half*)p;  p += (size_t)N * 64 * 2;
    __half* hB      = (__half*)p;  p += (size_t)N * 64 * 2;
    __half* agg16   = (__half*)p;  p += (size_t)N * 64 * 2;
    float*  pooled  = (float*)p;   p += 64 * 4;
    int*    bsums   = (int*)p;     p += 512 * 4;

    const int nbN = (N + 255) / 256;          // 391
    const int nbE = (E + 255) / 256;          // 3125
    const int nbW = (N + 3) / 4;              // gather64: wave-per-node
    const int nbG = (N + 63) / 64;            // mm64 blocks (64 nodes each)
    const int nbM6 = (int)(((long)N * 64 + 255) / 256);

    init_kernel<<<nbN, 256, 0, stream>>>(counts, pooled, N);
    count_slot_kernel<<<nbE, 256, 0, stream>>>(dst, counts, eslot, E);
    scan1_kernel<<<nbN, 256, 0, stream>>>(counts, bsums, N);
    scan2_kernel<<<1, 512, 0, stream>>>(bsums, nbN);
    scan3_kernel<<<nbN, 256, 0, stream>>>(counts, bsums, rowptr, N);
    fill2_kernel<<<nbE, 256, 0, stream>>>(src, dst, w, rowptr, eslot, csr, E);
    degdinv_kernel<<<nbN, 256, 0, stream>>>(csr, rowptr, dinv, N);
    norm_kernel<<<nbN, 256, 0, stream>>>(rowptr, dinv, csr, N);

    // layer 1: gather 6-wide, then mm 6->64 (+bias+relu) -> fp16 hA
    gather6_kernel<<<nbN, 256, 0, stream>>>(vf, rowptr, csr, dinv, g6, N);
    mm6_kernel<<<nbM6, 256, 0, stream>>>(g6, W1, b1, hA, N);
    // layers 2-4: gather (fp16 in/out) then GEMM; layer 4 fuses the max-pool
    gather64_kernel<<<nbW, 256, 0, stream>>>(hA, rowptr, csr, dinv, agg16, N);
    mm64_kernel<false><<<nbG, 256, 0, stream>>>(agg16, W2, b2, hB, nullptr, N);
    gather64_kernel<<<nbW, 256, 0, stream>>>(hB, rowptr, csr, dinv, agg16, N);
    mm64_kernel<false><<<nbG, 256, 0, stream>>>(agg16, W3, b3, hA, nullptr, N);
    gather64_kernel<<<nbW, 256, 0, stream>>>(hA, rowptr, csr, dinv, agg16, N);
    mm64_kernel<true><<<nbG, 256, 0, stream>>>(agg16, W4, b4, nullptr, pooled, N);

    out_kernel<<<1, 64, 0, stream>>>(pooled, Wr, br, out);
}

// Round 12
// 332.701 us; speedup vs baseline: 1.0561x; 1.0230x over previous
//
#include <hip/hip_runtime.h>
#include <hip/hip_fp16.h>
#include <math.h>

// GCN forward, reordered per-layer as x_{l} = relu((A x_{l-1}) @ W_l + b_l)
// (valid since A(xW) == (Ax)W). Then global max pool -> dot Wr.
//
// Split gather/mm per layer. h AND agg fp16; CSR packed int2{src, norm_bits}.
// Layer 4's mm fuses the max-pool via per-block LDS reduce -> blkmax row
// (NO atomics; 100k cross-XCD atomicMax measured 86us in R11); a single-block
// pool_out kernel reduces blkmax and emits the final dot product.

__global__ void init_kernel(int* counts, int N) {
    int i = blockIdx.x * blockDim.x + threadIdx.x;
    if (i < N) counts[i] = 0;
}

// pass 1: reserve a slot per edge within its dst row. 800k atomics total.
__global__ void count_slot_kernel(const int* __restrict__ dst, int* counts, int* eslot, int E) {
    int e = blockIdx.x * blockDim.x + threadIdx.x;
    if (e >= E) return;
    eslot[e] = atomicAdd(&counts[dst[e]], 1);
}

// ---- two-level exclusive scan of counts -> rowptr ----
__global__ void scan1_kernel(const int* __restrict__ counts, int* bsums, int N) {
    __shared__ int s[256];
    int t = threadIdx.x, i = blockIdx.x * 256 + t;
    s[t] = (i < N) ? counts[i] : 0;
    __syncthreads();
    for (int o = 128; o > 0; o >>= 1) {
        if (t < o) s[t] += s[t + o];
        __syncthreads();
    }
    if (t == 0) bsums[blockIdx.x] = s[0];
}

__global__ void scan2_kernel(int* bsums, int nb) {  // nb <= 512
    __shared__ int s[512];
    int t = threadIdx.x;
    int v = (t < nb) ? bsums[t] : 0;
    s[t] = v; __syncthreads();
    for (int o = 1; o < 512; o <<= 1) {
        int x = (t >= o) ? s[t - o] : 0;
        __syncthreads();
        s[t] += x;
        __syncthreads();
    }
    if (t < nb) bsums[t] = s[t] - v;  // exclusive
}

__global__ void scan3_kernel(const int* __restrict__ counts, const int* __restrict__ bsums,
                             int* rowptr, int N) {
    __shared__ int s[256];
    int t = threadIdx.x, i = blockIdx.x * 256 + t;
    int v = (i < N) ? counts[i] : 0;
    s[t] = v; __syncthreads();
    for (int o = 1; o < 256; o <<= 1) {
        int x = (t >= o) ? s[t - o] : 0;
        __syncthreads();
        s[t] += x;
        __syncthreads();
    }
    if (i <= N) rowptr[i] = bsums[blockIdx.x] + s[t] - v;  // rowptr[N] == E
}

// pass 2: atomic-free CSR fill using reserved slots. Packed int2{src, w_bits}.
__global__ void fill2_kernel(const int* __restrict__ src, const int* __restrict__ dst,
                             const float* __restrict__ w, const int* __restrict__ rowptr,
                             const int* __restrict__ eslot, int2* __restrict__ csr, int E) {
    int e = blockIdx.x * blockDim.x + threadIdx.x;
    if (e >= E) return;
    int p = rowptr[dst[e]] + eslot[e];
    csr[p] = make_int2(src[e], __float_as_int(w[e]));
}

// deg[i] = 1 + sum(w row) (self loop), dinv = 1/sqrt(deg). Coalesced, no atomics.
__global__ void degdinv_kernel(const int2* __restrict__ csr, const int* __restrict__ rowptr,
                               float* dinv, int N) {
    int i = blockIdx.x * blockDim.x + threadIdx.x;
    if (i >= N) return;
    float d = 1.0f;
    int jb = rowptr[i], je = rowptr[i + 1];
    for (int j = jb; j < je; ++j) d += __int_as_float(csr[j].y);
    dinv[i] = 1.0f / sqrtf(d);
}

// in-place: csr[j].y <- dinv[src] * w * dinv[i]
__global__ void norm_kernel(const int* __restrict__ rowptr, const float* __restrict__ dinv,
                            int2* __restrict__ csr, int N) {
    int i = blockIdx.x * blockDim.x + threadIdx.x;
    if (i >= N) return;
    float dn = dinv[i];
    int jb = rowptr[i], je = rowptr[i + 1];
    for (int j = jb; j < je; ++j) {
        int2 ed = csr[j];
        csr[j] = make_int2(ed.x, __float_as_int(dinv[ed.x] * __int_as_float(ed.y) * dn));
    }
}

// 6-wide gather over raw input features: g[i] = dinv[i]^2*x[i] + sum norm*x[src].
__global__ void gather6_kernel(const float* __restrict__ x, const int* __restrict__ rowptr,
                               const int2* __restrict__ csr,
                               const float* __restrict__ dinv, float* __restrict__ g, int N) {
    int i = blockIdx.x * blockDim.x + threadIdx.x;
    if (i >= N) return;
    float dn = dinv[i];
    float sc = dn * dn;
    float acc[6];
    {
        const float2* xr = (const float2*)(x + (size_t)i * 6);
        float2 a = xr[0], bv = xr[1], c = xr[2];
        acc[0] = sc * a.x; acc[1] = sc * a.y; acc[2] = sc * bv.x;
        acc[3] = sc * bv.y; acc[4] = sc * c.x; acc[5] = sc * c.y;
    }
    int jb = rowptr[i], je = rowptr[i + 1];
    for (int j = jb; j < je; ++j) {
        int2 ed = csr[j];
        float nm = __int_as_float(ed.y);
        const float2* xr = (const float2*)(x + (size_t)ed.x * 6);
        float2 a = xr[0], bv = xr[1], c = xr[2];
        acc[0] = fmaf(nm, a.x, acc[0]); acc[1] = fmaf(nm, a.y, acc[1]);
        acc[2] = fmaf(nm, bv.x, acc[2]); acc[3] = fmaf(nm, bv.y, acc[3]);
        acc[4] = fmaf(nm, c.x, acc[4]); acc[5] = fmaf(nm, c.y, acc[5]);
    }
#pragma unroll
    for (int f = 0; f < 6; ++f) g[(size_t)i * 6 + f] = acc[f];
}

// 64-wide gather over fp16 h: wave per node, 8 edge-groups x 8 lanes,
// uint4 (8 halves) per lane -> 8 random 128B rows in flight. fp32 accumulate,
// 3-step shfl reduce, group 0 writes the fp16 agg row (uint4).
__global__ void gather64_kernel(const __half* __restrict__ h, const int* __restrict__ rowptr,
                                const int2* __restrict__ csr,
                                const float* __restrict__ dinv, __half* __restrict__ agg, int N) {
    int wid = blockIdx.x * (blockDim.x >> 6) + (threadIdx.x >> 6);
    if (wid >= N) return;
    int lane = threadIdx.x & 63;
    int g = lane >> 3;      // edge group 0..7
    int l8 = lane & 7;      // 16B slot within 128B row
    float4 accA = {0.f, 0.f, 0.f, 0.f};
    float4 accB = {0.f, 0.f, 0.f, 0.f};
    if (g == 0) {
        float dn = dinv[wid];
        float sc = dn * dn;
        uint4 r = ((const uint4*)(h + (size_t)wid * 64))[l8];
        __half2 p0 = *(__half2*)&r.x, p1 = *(__half2*)&r.y;
        __half2 p2 = *(__half2*)&r.z, p3 = *(__half2*)&r.w;
        float2 f0 = __half22float2(p0), f1 = __half22float2(p1);
        float2 f2 = __half22float2(p2), f3 = __half22float2(p3);
        accA.x = sc * f0.x; accA.y = sc * f0.y; accA.z = sc * f1.x; accA.w = sc * f1.y;
        accB.x = sc * f2.x; accB.y = sc * f2.y; accB.z = sc * f3.x; accB.w = sc * f3.y;
    }
    int jb = rowptr[wid], je = rowptr[wid + 1];
    for (int j = jb + g; j < je; j += 8) {
        int2 ed = csr[j];
        float nm = __int_as_float(ed.y);
        uint4 r = ((const uint4*)(h + (size_t)ed.x * 64))[l8];
        __half2 p0 = *(__half2*)&r.x, p1 = *(__half2*)&r.y;
        __half2 p2 = *(__half2*)&r.z, p3 = *(__half2*)&r.w;
        float2 f0 = __half22float2(p0), f1 = __half22float2(p1);
        float2 f2 = __half22float2(p2), f3 = __half22float2(p3);
        accA.x = fmaf(nm, f0.x, accA.x); accA.y = fmaf(nm, f0.y, accA.y);
        accA.z = fmaf(nm, f1.x, accA.z); accA.w = fmaf(nm, f1.y, accA.w);
        accB.x = fmaf(nm, f2.x, accB.x); accB.y = fmaf(nm, f2.y, accB.y);
        accB.z = fmaf(nm, f3.x, accB.z); accB.w = fmaf(nm, f3.y, accB.w);
    }
#pragma unroll
    for (int o = 8; o <= 32; o <<= 1) {
        accA.x += __shfl_xor(accA.x, o);
        accA.y += __shfl_xor(accA.y, o);
        accA.z += __shfl_xor(accA.z, o);
        accA.w += __shfl_xor(accA.w, o);
        accB.x += __shfl_xor(accB.x, o);
        accB.y += __shfl_xor(accB.y, o);
        accB.z += __shfl_xor(accB.z, o);
        accB.w += __shfl_xor(accB.w, o);
    }
    if (g == 0) {
        __half2 q0 = __floats2half2_rn(accA.x, accA.y);
        __half2 q1 = __floats2half2_rn(accA.z, accA.w);
        __half2 q2 = __floats2half2_rn(accB.x, accB.y);
        __half2 q3 = __floats2half2_rn(accB.z, accB.w);
        uint4 pk;
        pk.x = *(unsigned int*)&q0; pk.y = *(unsigned int*)&q1;
        pk.z = *(unsigned int*)&q2; pk.w = *(unsigned int*)&q3;
        ((uint4*)(agg + (size_t)wid * 64))[l8] = pk;
    }
}

// h = relu(xin @ W + b), 64->64 fp16-in fp32-math. LDS-tiled vector GEMM;
// thread (ty,tx) = 4 nodes x 4 ch. FUSE_POOL: per-block LDS max-reduce ->
// one coalesced blkmax row write (NO atomics).
template<bool FUSE_POOL>
__global__ void __launch_bounds__(256)
__attribute__((amdgpu_waves_per_eu(2, 4)))
mm64_kernel(const __half* __restrict__ xin, const float* __restrict__ W,
            const float* __restrict__ b, __half* __restrict__ h_out,
            float* blkmax, int N) {
    __shared__ float xl[64 * 68];
    __shared__ float Wt[64 * 68];
    const int tid = threadIdx.x;
    const long nb = (long)blockIdx.x * 64;

#pragma unroll
    for (int r = 0; r < 4; ++r) {
        int q = tid + 256 * r;          // float4 index 0..1023
        int row = q >> 4, c4 = q & 15;
        ((float4*)&Wt[row * 68 + c4 * 4])[0] = ((const float4*)W)[q];
    }
#pragma unroll
    for (int r = 0; r < 2; ++r) {
        int q = tid + 256 * r;          // uint4 index 0..511 (64 rows x 8)
        int row = q >> 3, u4 = q & 7;
        long n = nb + row;
        float4 vA = {0.f, 0.f, 0.f, 0.f}, vB = {0.f, 0.f, 0.f, 0.f};
        if (n < N) {
            uint4 rr = ((const uint4*)(xin + n * 64))[u4];
            __half2 p0 = *(__half2*)&rr.x, p1 = *(__half2*)&rr.y;
            __half2 p2 = *(__half2*)&rr.z, p3 = *(__half2*)&rr.w;
            float2 f0 = __half22float2(p0), f1 = __half22float2(p1);
            float2 f2 = __half22float2(p2), f3 = __half22float2(p3);
            vA.x = f0.x; vA.y = f0.y; vA.z = f1.x; vA.w = f1.y;
            vB.x = f2.x; vB.y = f2.y; vB.z = f3.x; vB.w = f3.y;
        }
        float* dstp = &xl[row * 68 + u4 * 8];
        ((float4*)dstp)[0] = vA;
        ((float4*)dstp)[1] = vB;
    }
    __syncthreads();

    const int tx = tid & 15;   // channel group: ch = tx*4..+3
    const int ty = tid >> 4;   // node group:    n = ty*4..+3

    float4 acc0 = {0,0,0,0}, acc1 = {0,0,0,0}, acc2 = {0,0,0,0}, acc3 = {0,0,0,0};
#pragma unroll 4
    for (int kc = 0; kc < 16; ++kc) {
        float4 w0 = *(const float4*)&Wt[(kc * 4 + 0) * 68 + tx * 4];
        float4 w1 = *(const float4*)&Wt[(kc * 4 + 1) * 68 + tx * 4];
        float4 w2 = *(const float4*)&Wt[(kc * 4 + 2) * 68 + tx * 4];
        float4 w3 = *(const float4*)&Wt[(kc * 4 + 3) * 68 + tx * 4];
        float4 x0 = *(const float4*)&xl[(ty * 4 + 0) * 68 + kc * 4];
        float4 x1 = *(const float4*)&xl[(ty * 4 + 1) * 68 + kc * 4];
        float4 x2 = *(const float4*)&xl[(ty * 4 + 2) * 68 + kc * 4];
        float4 x3 = *(const float4*)&xl[(ty * 4 + 3) * 68 + kc * 4];
#define MMSTEP(A, X) \
        A.x = fmaf(X.x, w0.x, A.x); A.y = fmaf(X.x, w0.y, A.y); A.z = fmaf(X.x, w0.z, A.z); A.w = fmaf(X.x, w0.w, A.w); \
        A.x = fmaf(X.y, w1.x, A.x); A.y = fmaf(X.y, w1.y, A.y); A.z = fmaf(X.y, w1.z, A.z); A.w = fmaf(X.y, w1.w, A.w); \
        A.x = fmaf(X.z, w2.x, A.x); A.y = fmaf(X.z, w2.y, A.y); A.z = fmaf(X.z, w2.z, A.z); A.w = fmaf(X.z, w2.w, A.w); \
        A.x = fmaf(X.w, w3.x, A.x); A.y = fmaf(X.w, w3.y, A.y); A.z = fmaf(X.w, w3.z, A.z); A.w = fmaf(X.w, w3.w, A.w);
        MMSTEP(acc0, x0) MMSTEP(acc1, x1) MMSTEP(acc2, x2) MMSTEP(acc3, x3)
#undef MMSTEP
    }

    float4 vb = ((const float4*)b)[tx];
    if (!FUSE_POOL) {
#define MMOUT(A, I) { \
        long n = nb + ty * 4 + I; \
        if (n < N) { \
            float o0 = fmaxf(A.x + vb.x, 0.f), o1 = fmaxf(A.y + vb.y, 0.f); \
            float o2 = fmaxf(A.z + vb.z, 0.f), o3 = fmaxf(A.w + vb.w, 0.f); \
            __half2 p0 = __floats2half2_rn(o0, o1), p1 = __floats2half2_rn(o2, o3); \
            uint2 pk; pk.x = *(unsigned int*)&p0; pk.y = *(unsigned int*)&p1; \
            ((uint2*)(h_out + n * 64))[tx] = pk; \
        } }
        MMOUT(acc0, 0) MMOUT(acc1, 1) MMOUT(acc2, 2) MMOUT(acc3, 3)
#undef MMOUT
    } else {
        float4 m = {0.f, 0.f, 0.f, 0.f};
#define MMMAX(A, I) { \
        long n = nb + ty * 4 + I; \
        if (n < N) { \
            m.x = fmaxf(m.x, A.x + vb.x); m.y = fmaxf(m.y, A.y + vb.y); \
            m.z = fmaxf(m.z, A.z + vb.z); m.w = fmaxf(m.w, A.w + vb.w); \
        } }
        MMMAX(acc0, 0) MMMAX(acc1, 1) MMMAX(acc2, 2) MMMAX(acc3, 3)
#undef MMMAX
        __syncthreads();                        // done reading xl
        ((float4*)xl)[ty * 16 + tx] = m;        // xl as [16 ty][16 tx] float4
        __syncthreads();
#pragma unroll
        for (int off = 8; off > 0; off >>= 1) {
            if (ty < off) {
                float4 a = ((float4*)xl)[ty * 16 + tx];
                float4 c = ((float4*)xl)[(ty + off) * 16 + tx];
                a.x = fmaxf(a.x, c.x); a.y = fmaxf(a.y, c.y);
                a.z = fmaxf(a.z, c.z); a.w = fmaxf(a.w, c.w);
                ((float4*)xl)[ty * 16 + tx] = a;
            }
            __syncthreads();
        }
        if (ty == 0)   // one coalesced 256B row store, zero atomics
            ((float4*)(blkmax + (size_t)blockIdx.x * 64))[tx] = ((float4*)xl)[tx];
    }
}

// h[n*64+c] = relu(xin[n] @ W[:,c] + b[c]) -> fp16, 6->64. Thread per (node,ch).
__global__ void __launch_bounds__(256)
mm6_kernel(const float* __restrict__ xin, const float* __restrict__ W,
           const float* __restrict__ b, __half* __restrict__ h, int N) {
    long idx = (long)blockIdx.x * blockDim.x + threadIdx.x;  // node*64 + ch
    if (idx >= (long)N * 64) return;
    long n = idx >> 6;
    int c = (int)(idx & 63);
    const float* xr = xin + n * 6;
    float a = b[c];
    a = fmaf(xr[0], W[0 * 64 + c], a);
    a = fmaf(xr[1], W[1 * 64 + c], a);
    a = fmaf(xr[2], W[2 * 64 + c], a);
    a = fmaf(xr[3], W[3 * 64 + c], a);
    a = fmaf(xr[4], W[4 * 64 + c], a);
    a = fmaf(xr[5], W[5 * 64 + c], a);
    h[idx] = __float2half(fmaxf(a, 0.0f));
}

// Reduce blkmax[nrows][64] -> pooled[64], then out = pooled . Wr + br.
// Single block, 256 threads: channel = tid&63, quarter = tid>>6.
__global__ void pool_out_kernel(const float* __restrict__ blkmax, int nrows,
                                const float* __restrict__ Wr, const float* __restrict__ br,
                                float* out) {
    __shared__ float red[256];
    int tid = threadIdx.x;
    int c = tid & 63, part = tid >> 6;
    float m = 0.0f;
    for (int r = part; r < nrows; r += 4)
        m = fmaxf(m, blkmax[(size_t)r * 64 + c]);
    red[tid] = m;
    __syncthreads();
    if (tid < 64) {
        m = fmaxf(fmaxf(red[tid], red[tid + 64]), fmaxf(red[tid + 128], red[tid + 192]));
        float v = m * Wr[tid];
#pragma unroll
        for (int o = 32; o > 0; o >>= 1) v += __shfl_xor(v, o);
        if (tid == 0) out[0] = v + br[0];
    }
}

extern "C" void kernel_launch(void* const* d_in, const int* in_sizes, int n_in,
                              void* d_out, int out_size, void* d_ws, size_t ws_size,
                              hipStream_t stream) {
    const float* vf = (const float*)d_in[0];
    const int* edges = (const int*)d_in[1];
    const float* w = (const float*)d_in[2];
    const float* W1 = (const float*)d_in[3];  const float* b1 = (const float*)d_in[4];
    const float* W2 = (const float*)d_in[5];  const float* b2 = (const float*)d_in[6];
    const float* W3 = (const float*)d_in[7];  const float* b3 = (const float*)d_in[8];
    const float* W4 = (const float*)d_in[9];  const float* b4 = (const float*)d_in[10];
    const float* Wr = (const float*)d_in[11]; const float* br = (const float*)d_in[12];
    float* out = (float*)d_out;

    const int FIN = 6;
    const int N = in_sizes[0] / FIN;   // 100000
    const int E = in_sizes[2];         // 800000
    const int* src = edges;
    const int* dst = edges + E;

    const int nbN = (N + 255) / 256;          // 391
    const int nbE = (E + 255) / 256;          // 3125
    const int nbW = (N + 3) / 4;              // gather64: wave-per-node
    const int nbG = (N + 63) / 64;            // mm64 blocks (64 nodes each)
    const int nbM6 = (int)(((long)N * 64 + 255) / 256);

    char* p = (char*)d_ws;
    float*  dinv    = (float*)p;   p += (size_t)N * 4;
    int*    rowptr  = (int*)p;     p += (size_t)(N + 1) * 4;
    int*    counts  = (int*)p;     p += (size_t)N * 4;
    int*    eslot   = (int*)p;     p += (size_t)E * 4;
    int2*   csr     = (int2*)p;    p += (size_t)E * 8;   // {src, w/norm bits}
    float*  g6      = (float*)p;   p += (size_t)N * 6 * 4;
    __half* hA      = (__half*)p;  p += (size_t)N * 64 * 2;
    __half* hB      = (__half*)p;  p += (size_t)N * 64 * 2;
    __half* agg16   = (__half*)p;  p += (size_t)N * 64 * 2;
    float*  blkmax  = (float*)p;   p += (size_t)nbG * 64 * 4;
    int*    bsums   = (int*)p;     p += 512 * 4;

    init_kernel<<<nbN, 256, 0, stream>>>(counts, N);
    count_slot_kernel<<<nbE, 256, 0, stream>>>(dst, counts, eslot, E);
    scan1_kernel<<<nbN, 256, 0, stream>>>(counts, bsums, N);
    scan2_kernel<<<1, 512, 0, stream>>>(bsums, nbN);
    scan3_kernel<<<nbN, 256, 0, stream>>>(counts, bsums, rowptr, N);
    fill2_kernel<<<nbE, 256, 0, stream>>>(src, dst, w, rowptr, eslot, csr, E);
    degdinv_kernel<<<nbN, 256, 0, stream>>>(csr, rowptr, dinv, N);
    norm_kernel<<<nbN, 256, 0, stream>>>(rowptr, dinv, csr, N);

    // layer 1: gather 6-wide, then mm 6->64 (+bias+relu) -> fp16 hA
    gather6_kernel<<<nbN, 256, 0, stream>>>(vf, rowptr, csr, dinv, g6, N);
    mm6_kernel<<<nbM6, 256, 0, stream>>>(g6, W1, b1, hA, N);
    // layers 2-4: gather (fp16 in/out) then GEMM; layer 4 fuses max-pool (no atomics)
    gather64_kernel<<<nbW, 256, 0, stream>>>(hA, rowptr, csr, dinv, agg16, N);
    mm64_kernel<false><<<nbG, 256, 0, stream>>>(agg16, W2, b2, hB, nullptr, N);
    gather64_kernel<<<nbW, 256, 0, stream>>>(hB, rowptr, csr, dinv, agg16, N);
    mm64_kernel<false><<<nbG, 256, 0, stream>>>(agg16, W3, b3, hA, nullptr, N);
    gather64_kernel<<<nbW, 256, 0, stream>>>(hA, rowptr, csr, dinv, agg16, N);
    mm64_kernel<true><<<nbG, 256, 0, stream>>>(agg16, W4, b4, nullptr, blkmax, N);

    pool_out_kernel<<<1, 256, 0, stream>>>(blkmax, nbG, Wr, br, out);
}

// Round 13
// 277.262 us; speedup vs baseline: 1.2673x; 1.2000x over previous
//
#include <hip/hip_runtime.h>
#include <hip/hip_fp16.h>
#include <math.h>

// GCN forward, reordered per-layer as x_{l} = relu((A x_{l-1}) @ W_l + b_l)
// (valid since A(xW) == (Ax)W). Then global max pool -> dot Wr.
//
// Split gather/mm per layer. h AND agg fp16; CSR packed int2{src, norm_bits}.
// Layer 4's mm fuses max-pool -> per-block blkmax rows (no atomics);
// blkmax is reduced in TWO stages (64-block partial + 1-block final) --
// a single-block reduce of 400KB measured 66us (latency-bound, R12).

__global__ void init_kernel(int* counts, int N) {
    int i = blockIdx.x * blockDim.x + threadIdx.x;
    if (i < N) counts[i] = 0;
}

// pass 1: reserve a slot per edge within its dst row. 800k atomics total.
__global__ void count_slot_kernel(const int* __restrict__ dst, int* counts, int* eslot, int E) {
    int e = blockIdx.x * blockDim.x + threadIdx.x;
    if (e >= E) return;
    eslot[e] = atomicAdd(&counts[dst[e]], 1);
}

// ---- two-level exclusive scan of counts -> rowptr ----
__global__ void scan1_kernel(const int* __restrict__ counts, int* bsums, int N) {
    __shared__ int s[256];
    int t = threadIdx.x, i = blockIdx.x * 256 + t;
    s[t] = (i < N) ? counts[i] : 0;
    __syncthreads();
    for (int o = 128; o > 0; o >>= 1) {
        if (t < o) s[t] += s[t + o];
        __syncthreads();
    }
    if (t == 0) bsums[blockIdx.x] = s[0];
}

__global__ void scan2_kernel(int* bsums, int nb) {  // nb <= 512
    __shared__ int s[512];
    int t = threadIdx.x;
    int v = (t < nb) ? bsums[t] : 0;
    s[t] = v; __syncthreads();
    for (int o = 1; o < 512; o <<= 1) {
        int x = (t >= o) ? s[t - o] : 0;
        __syncthreads();
        s[t] += x;
        __syncthreads();
    }
    if (t < nb) bsums[t] = s[t] - v;  // exclusive
}

__global__ void scan3_kernel(const int* __restrict__ counts, const int* __restrict__ bsums,
                             int* rowptr, int N) {
    __shared__ int s[256];
    int t = threadIdx.x, i = blockIdx.x * 256 + t;
    int v = (i < N) ? counts[i] : 0;
    s[t] = v; __syncthreads();
    for (int o = 1; o < 256; o <<= 1) {
        int x = (t >= o) ? s[t - o] : 0;
        __syncthreads();
        s[t] += x;
        __syncthreads();
    }
    if (i <= N) rowptr[i] = bsums[blockIdx.x] + s[t] - v;  // rowptr[N] == E
}

// pass 2: atomic-free CSR fill using reserved slots. Packed int2{src, w_bits}.
__global__ void fill2_kernel(const int* __restrict__ src, const int* __restrict__ dst,
                             const float* __restrict__ w, const int* __restrict__ rowptr,
                             const int* __restrict__ eslot, int2* __restrict__ csr, int E) {
    int e = blockIdx.x * blockDim.x + threadIdx.x;
    if (e >= E) return;
    int p = rowptr[dst[e]] + eslot[e];
    csr[p] = make_int2(src[e], __float_as_int(w[e]));
}

// deg[i] = 1 + sum(w row) (self loop), dinv = 1/sqrt(deg). Coalesced, no atomics.
__global__ void degdinv_kernel(const int2* __restrict__ csr, const int* __restrict__ rowptr,
                               float* dinv, int N) {
    int i = blockIdx.x * blockDim.x + threadIdx.x;
    if (i >= N) return;
    float d = 1.0f;
    int jb = rowptr[i], je = rowptr[i + 1];
    for (int j = jb; j < je; ++j) d += __int_as_float(csr[j].y);
    dinv[i] = 1.0f / sqrtf(d);
}

// in-place: csr[j].y <- dinv[src] * w * dinv[i]
__global__ void norm_kernel(const int* __restrict__ rowptr, const float* __restrict__ dinv,
                            int2* __restrict__ csr, int N) {
    int i = blockIdx.x * blockDim.x + threadIdx.x;
    if (i >= N) return;
    float dn = dinv[i];
    int jb = rowptr[i], je = rowptr[i + 1];
    for (int j = jb; j < je; ++j) {
        int2 ed = csr[j];
        csr[j] = make_int2(ed.x, __float_as_int(dinv[ed.x] * __int_as_float(ed.y) * dn));
    }
}

// 6-wide gather over raw input features: g[i] = dinv[i]^2*x[i] + sum norm*x[src].
__global__ void gather6_kernel(const float* __restrict__ x, const int* __restrict__ rowptr,
                               const int2* __restrict__ csr,
                               const float* __restrict__ dinv, float* __restrict__ g, int N) {
    int i = blockIdx.x * blockDim.x + threadIdx.x;
    if (i >= N) return;
    float dn = dinv[i];
    float sc = dn * dn;
    float acc[6];
    {
        const float2* xr = (const float2*)(x + (size_t)i * 6);
        float2 a = xr[0], bv = xr[1], c = xr[2];
        acc[0] = sc * a.x; acc[1] = sc * a.y; acc[2] = sc * bv.x;
        acc[3] = sc * bv.y; acc[4] = sc * c.x; acc[5] = sc * c.y;
    }
    int jb = rowptr[i], je = rowptr[i + 1];
    for (int j = jb; j < je; ++j) {
        int2 ed = csr[j];
        float nm = __int_as_float(ed.y);
        const float2* xr = (const float2*)(x + (size_t)ed.x * 6);
        float2 a = xr[0], bv = xr[1], c = xr[2];
        acc[0] = fmaf(nm, a.x, acc[0]); acc[1] = fmaf(nm, a.y, acc[1]);
        acc[2] = fmaf(nm, bv.x, acc[2]); acc[3] = fmaf(nm, bv.y, acc[3]);
        acc[4] = fmaf(nm, c.x, acc[4]); acc[5] = fmaf(nm, c.y, acc[5]);
    }
#pragma unroll
    for (int f = 0; f < 6; ++f) g[(size_t)i * 6 + f] = acc[f];
}

// 64-wide gather over fp16 h: wave per node, 8 edge-groups x 8 lanes,
// uint4 (8 halves) per lane -> 8 random 128B rows in flight. fp32 accumulate,
// 3-step shfl reduce, group 0 writes the fp16 agg row (uint4).
__global__ void gather64_kernel(const __half* __restrict__ h, const int* __restrict__ rowptr,
                                const int2* __restrict__ csr,
                                const float* __restrict__ dinv, __half* __restrict__ agg, int N) {
    int wid = blockIdx.x * (blockDim.x >> 6) + (threadIdx.x >> 6);
    if (wid >= N) return;
    int lane = threadIdx.x & 63;
    int g = lane >> 3;      // edge group 0..7
    int l8 = lane & 7;      // 16B slot within 128B row
    float4 accA = {0.f, 0.f, 0.f, 0.f};
    float4 accB = {0.f, 0.f, 0.f, 0.f};
    if (g == 0) {
        float dn = dinv[wid];
        float sc = dn * dn;
        uint4 r = ((const uint4*)(h + (size_t)wid * 64))[l8];
        __half2 p0 = *(__half2*)&r.x, p1 = *(__half2*)&r.y;
        __half2 p2 = *(__half2*)&r.z, p3 = *(__half2*)&r.w;
        float2 f0 = __half22float2(p0), f1 = __half22float2(p1);
        float2 f2 = __half22float2(p2), f3 = __half22float2(p3);
        accA.x = sc * f0.x; accA.y = sc * f0.y; accA.z = sc * f1.x; accA.w = sc * f1.y;
        accB.x = sc * f2.x; accB.y = sc * f2.y; accB.z = sc * f3.x; accB.w = sc * f3.y;
    }
    int jb = rowptr[wid], je = rowptr[wid + 1];
    for (int j = jb + g; j < je; j += 8) {
        int2 ed = csr[j];
        float nm = __int_as_float(ed.y);
        uint4 r = ((const uint4*)(h + (size_t)ed.x * 64))[l8];
        __half2 p0 = *(__half2*)&r.x, p1 = *(__half2*)&r.y;
        __half2 p2 = *(__half2*)&r.z, p3 = *(__half2*)&r.w;
        float2 f0 = __half22float2(p0), f1 = __half22float2(p1);
        float2 f2 = __half22float2(p2), f3 = __half22float2(p3);
        accA.x = fmaf(nm, f0.x, accA.x); accA.y = fmaf(nm, f0.y, accA.y);
        accA.z = fmaf(nm, f1.x, accA.z); accA.w = fmaf(nm, f1.y, accA.w);
        accB.x = fmaf(nm, f2.x, accB.x); accB.y = fmaf(nm, f2.y, accB.y);
        accB.z = fmaf(nm, f3.x, accB.z); accB.w = fmaf(nm, f3.y, accB.w);
    }
#pragma unroll
    for (int o = 8; o <= 32; o <<= 1) {
        accA.x += __shfl_xor(accA.x, o);
        accA.y += __shfl_xor(accA.y, o);
        accA.z += __shfl_xor(accA.z, o);
        accA.w += __shfl_xor(accA.w, o);
        accB.x += __shfl_xor(accB.x, o);
        accB.y += __shfl_xor(accB.y, o);
        accB.z += __shfl_xor(accB.z, o);
        accB.w += __shfl_xor(accB.w, o);
    }
    if (g == 0) {
        __half2 q0 = __floats2half2_rn(accA.x, accA.y);
        __half2 q1 = __floats2half2_rn(accA.z, accA.w);
        __half2 q2 = __floats2half2_rn(accB.x, accB.y);
        __half2 q3 = __floats2half2_rn(accB.z, accB.w);
        uint4 pk;
        pk.x = *(unsigned int*)&q0; pk.y = *(unsigned int*)&q1;
        pk.z = *(unsigned int*)&q2; pk.w = *(unsigned int*)&q3;
        ((uint4*)(agg + (size_t)wid * 64))[l8] = pk;
    }
}

// h = relu(xin @ W + b), 64->64 fp16-in fp32-math. LDS-tiled vector GEMM;
// thread (ty,tx) = 4 nodes x 4 ch. FUSE_POOL: per-block LDS max-reduce ->
// one coalesced blkmax row write (NO atomics).
template<bool FUSE_POOL>
__global__ void __launch_bounds__(256)
__attribute__((amdgpu_waves_per_eu(2, 4)))
mm64_kernel(const __half* __restrict__ xin, const float* __restrict__ W,
            const float* __restrict__ b, __half* __restrict__ h_out,
            float* blkmax, int N) {
    __shared__ float xl[64 * 68];
    __shared__ float Wt[64 * 68];
    const int tid = threadIdx.x;
    const long nb = (long)blockIdx.x * 64;

#pragma unroll
    for (int r = 0; r < 4; ++r) {
        int q = tid + 256 * r;          // float4 index 0..1023
        int row = q >> 4, c4 = q & 15;
        ((float4*)&Wt[row * 68 + c4 * 4])[0] = ((const float4*)W)[q];
    }
#pragma unroll
    for (int r = 0; r < 2; ++r) {
        int q = tid + 256 * r;          // uint4 index 0..511 (64 rows x 8)
        int row = q >> 3, u4 = q & 7;
        long n = nb + row;
        float4 vA = {0.f, 0.f, 0.f, 0.f}, vB = {0.f, 0.f, 0.f, 0.f};
        if (n < N) {
            uint4 rr = ((const uint4*)(xin + n * 64))[u4];
            __half2 p0 = *(__half2*)&rr.x, p1 = *(__half2*)&rr.y;
            __half2 p2 = *(__half2*)&rr.z, p3 = *(__half2*)&rr.w;
            float2 f0 = __half22float2(p0), f1 = __half22float2(p1);
            float2 f2 = __half22float2(p2), f3 = __half22float2(p3);
            vA.x = f0.x; vA.y = f0.y; vA.z = f1.x; vA.w = f1.y;
            vB.x = f2.x; vB.y = f2.y; vB.z = f3.x; vB.w = f3.y;
        }
        float* dstp = &xl[row * 68 + u4 * 8];
        ((float4*)dstp)[0] = vA;
        ((float4*)dstp)[1] = vB;
    }
    __syncthreads();

    const int tx = tid & 15;   // channel group: ch = tx*4..+3
    const int ty = tid >> 4;   // node group:    n = ty*4..+3

    float4 acc0 = {0,0,0,0}, acc1 = {0,0,0,0}, acc2 = {0,0,0,0}, acc3 = {0,0,0,0};
#pragma unroll 4
    for (int kc = 0; kc < 16; ++kc) {
        float4 w0 = *(const float4*)&Wt[(kc * 4 + 0) * 68 + tx * 4];
        float4 w1 = *(const float4*)&Wt[(kc * 4 + 1) * 68 + tx * 4];
        float4 w2 = *(const float4*)&Wt[(kc * 4 + 2) * 68 + tx * 4];
        float4 w3 = *(const float4*)&Wt[(kc * 4 + 3) * 68 + tx * 4];
        float4 x0 = *(const float4*)&xl[(ty * 4 + 0) * 68 + kc * 4];
        float4 x1 = *(const float4*)&xl[(ty * 4 + 1) * 68 + kc * 4];
        float4 x2 = *(const float4*)&xl[(ty * 4 + 2) * 68 + kc * 4];
        float4 x3 = *(const float4*)&xl[(ty * 4 + 3) * 68 + kc * 4];
#define MMSTEP(A, X) \
        A.x = fmaf(X.x, w0.x, A.x); A.y = fmaf(X.x, w0.y, A.y); A.z = fmaf(X.x, w0.z, A.z); A.w = fmaf(X.x, w0.w, A.w); \
        A.x = fmaf(X.y, w1.x, A.x); A.y = fmaf(X.y, w1.y, A.y); A.z = fmaf(X.y, w1.z, A.z); A.w = fmaf(X.y, w1.w, A.w); \
        A.x = fmaf(X.z, w2.x, A.x); A.y = fmaf(X.z, w2.y, A.y); A.z = fmaf(X.z, w2.z, A.z); A.w = fmaf(X.z, w2.w, A.w); \
        A.x = fmaf(X.w, w3.x, A.x); A.y = fmaf(X.w, w3.y, A.y); A.z = fmaf(X.w, w3.z, A.z); A.w = fmaf(X.w, w3.w, A.w);
        MMSTEP(acc0, x0) MMSTEP(acc1, x1) MMSTEP(acc2, x2) MMSTEP(acc3, x3)
#undef MMSTEP
    }

    float4 vb = ((const float4*)b)[tx];
    if (!FUSE_POOL) {
#define MMOUT(A, I) { \
        long n = nb + ty * 4 + I; \
        if (n < N) { \
            float o0 = fmaxf(A.x + vb.x, 0.f), o1 = fmaxf(A.y + vb.y, 0.f); \
            float o2 = fmaxf(A.z + vb.z, 0.f), o3 = fmaxf(A.w + vb.w, 0.f); \
            __half2 p0 = __floats2half2_rn(o0, o1), p1 = __floats2half2_rn(o2, o3); \
            uint2 pk; pk.x = *(unsigned int*)&p0; pk.y = *(unsigned int*)&p1; \
            ((uint2*)(h_out + n * 64))[tx] = pk; \
        } }
        MMOUT(acc0, 0) MMOUT(acc1, 1) MMOUT(acc2, 2) MMOUT(acc3, 3)
#undef MMOUT
    } else {
        float4 m = {0.f, 0.f, 0.f, 0.f};
#define MMMAX(A, I) { \
        long n = nb + ty * 4 + I; \
        if (n < N) { \
            m.x = fmaxf(m.x, A.x + vb.x); m.y = fmaxf(m.y, A.y + vb.y); \
            m.z = fmaxf(m.z, A.z + vb.z); m.w = fmaxf(m.w, A.w + vb.w); \
        } }
        MMMAX(acc0, 0) MMMAX(acc1, 1) MMMAX(acc2, 2) MMMAX(acc3, 3)
#undef MMMAX
        __syncthreads();                        // done reading xl
        ((float4*)xl)[ty * 16 + tx] = m;        // xl as [16 ty][16 tx] float4
        __syncthreads();
#pragma unroll
        for (int off = 8; off > 0; off >>= 1) {
            if (ty < off) {
                float4 a = ((float4*)xl)[ty * 16 + tx];
                float4 c = ((float4*)xl)[(ty + off) * 16 + tx];
                a.x = fmaxf(a.x, c.x); a.y = fmaxf(a.y, c.y);
                a.z = fmaxf(a.z, c.z); a.w = fmaxf(a.w, c.w);
                ((float4*)xl)[ty * 16 + tx] = a;
            }
            __syncthreads();
        }
        if (ty == 0)   // one coalesced 256B row store, zero atomics
            ((float4*)(blkmax + (size_t)blockIdx.x * 64))[tx] = ((float4*)xl)[tx];
    }
}

// h[n*64+c] = relu(xin[n] @ W[:,c] + b[c]) -> fp16, 6->64. Thread per (node,ch).
__global__ void __launch_bounds__(256)
mm6_kernel(const float* __restrict__ xin, const float* __restrict__ W,
           const float* __restrict__ b, __half* __restrict__ h, int N) {
    long idx = (long)blockIdx.x * blockDim.x + threadIdx.x;  // node*64 + ch
    if (idx >= (long)N * 64) return;
    long n = idx >> 6;
    int c = (int)(idx & 63);
    const float* xr = xin + n * 6;
    float a = b[c];
    a = fmaf(xr[0], W[0 * 64 + c], a);
    a = fmaf(xr[1], W[1 * 64 + c], a);
    a = fmaf(xr[2], W[2 * 64 + c], a);
    a = fmaf(xr[3], W[3 * 64 + c], a);
    a = fmaf(xr[4], W[4 * 64 + c], a);
    a = fmaf(xr[5], W[5 * 64 + c], a);
    h[idx] = __float2half(fmaxf(a, 0.0f));
}

// Stage 1: 64 blocks; block r max-reduces rows r, r+64, ... of blkmax
// into part[r][64]. Loads are independent -> latency overlapped.
__global__ void pool_part_kernel(const float* __restrict__ blkmax, int nrows,
                                 float* __restrict__ part) {
    int tid = threadIdx.x;
    int c = tid & 63, q = tid >> 6;          // q = 0..3
    int r0 = blockIdx.x + q * 64;            // rows strided by 256 per thread
    float m = 0.0f;
    for (int r = r0; r < nrows; r += 256)
        m = fmaxf(m, blkmax[(size_t)r * 64 + c]);
    __shared__ float red[256];
    red[tid] = m;
    __syncthreads();
    if (tid < 64) {
        m = fmaxf(fmaxf(red[tid], red[tid + 64]), fmaxf(red[tid + 128], red[tid + 192]));
        part[(size_t)blockIdx.x * 64 + tid] = m;
    }
}

// Stage 2: single block reduces part[64][64] (16KB, L2-hot) -> out scalar.
__global__ void pool_out_kernel(const float* __restrict__ part,
                                const float* __restrict__ Wr, const float* __restrict__ br,
                                float* out) {
    __shared__ float red[256];
    int tid = threadIdx.x;
    int c = tid & 63, q = tid >> 6;
    float m = 0.0f;
    for (int r = q; r < 64; r += 4)
        m = fmaxf(m, part[(size_t)r * 64 + c]);
    red[tid] = m;
    __syncthreads();
    if (tid < 64) {
        m = fmaxf(fmaxf(red[tid], red[tid + 64]), fmaxf(red[tid + 128], red[tid + 192]));
        float v = m * Wr[tid];
#pragma unroll
        for (int o = 32; o > 0; o >>= 1) v += __shfl_xor(v, o);
        if (tid == 0) out[0] = v + br[0];
    }
}

extern "C" void kernel_launch(void* const* d_in, const int* in_sizes, int n_in,
                              void* d_out, int out_size, void* d_ws, size_t ws_size,
                              hipStream_t stream) {
    const float* vf = (const float*)d_in[0];
    const int* edges = (const int*)d_in[1];
    const float* w = (const float*)d_in[2];
    const float* W1 = (const float*)d_in[3];  const float* b1 = (const float*)d_in[4];
    const float* W2 = (const float*)d_in[5];  const float* b2 = (const float*)d_in[6];
    const float* W3 = (const float*)d_in[7];  const float* b3 = (const float*)d_in[8];
    const float* W4 = (const float*)d_in[9];  const float* b4 = (const float*)d_in[10];
    const float* Wr = (const float*)d_in[11]; const float* br = (const float*)d_in[12];
    float* out = (float*)d_out;

    const int FIN = 6;
    const int N = in_sizes[0] / FIN;   // 100000
    const int E = in_sizes[2];         // 800000
    const int* src = edges;
    const int* dst = edges + E;

    const int nbN = (N + 255) / 256;          // 391
    const int nbE = (E + 255) / 256;          // 3125
    const int nbW = (N + 3) / 4;              // gather64: wave-per-node
    const int nbG = (N + 63) / 64;            // mm64 blocks (64 nodes each)
    const int nbM6 = (int)(((long)N * 64 + 255) / 256);

    char* p = (char*)d_ws;
    float*  dinv    = (float*)p;   p += (size_t)N * 4;
    int*    rowptr  = (int*)p;     p += (size_t)(N + 1) * 4;
    int*    counts  = (int*)p;     p += (size_t)N * 4;
    int*    eslot   = (int*)p;     p += (size_t)E * 4;
    int2*   csr     = (int2*)p;    p += (size_t)E * 8;   // {src, w/norm bits}
    float*  g6      = (float*)p;   p += (size_t)N * 6 * 4;
    __half* hA      = (__half*)p;  p += (size_t)N * 64 * 2;
    __half* hB      = (__half*)p;  p += (size_t)N * 64 * 2;
    __half* agg16   = (__half*)p;  p += (size_t)N * 64 * 2;
    float*  blkmax  = (float*)p;   p += (size_t)nbG * 64 * 4;
    float*  part    = (float*)p;   p += (size_t)64 * 64 * 4;
    int*    bsums   = (int*)p;     p += 512 * 4;

    init_kernel<<<nbN, 256, 0, stream>>>(counts, N);
    count_slot_kernel<<<nbE, 256, 0, stream>>>(dst, counts, eslot, E);
    scan1_kernel<<<nbN, 256, 0, stream>>>(counts, bsums, N);
    scan2_kernel<<<1, 512, 0, stream>>>(bsums, nbN);
    scan3_kernel<<<nbN, 256, 0, stream>>>(counts, bsums, rowptr, N);
    fill2_kernel<<<nbE, 256, 0, stream>>>(src, dst, w, rowptr, eslot, csr, E);
    degdinv_kernel<<<nbN, 256, 0, stream>>>(csr, rowptr, dinv, N);
    norm_kernel<<<nbN, 256, 0, stream>>>(rowptr, dinv, csr, N);

    // layer 1: gather 6-wide, then mm 6->64 (+bias+relu) -> fp16 hA
    gather6_kernel<<<nbN, 256, 0, stream>>>(vf, rowptr, csr, dinv, g6, N);
    mm6_kernel<<<nbM6, 256, 0, stream>>>(g6, W1, b1, hA, N);
    // layers 2-4: gather (fp16 in/out) then GEMM; layer 4 fuses max-pool (no atomics)
    gather64_kernel<<<nbW, 256, 0, stream>>>(hA, rowptr, csr, dinv, agg16, N);
    mm64_kernel<false><<<nbG, 256, 0, stream>>>(agg16, W2, b2, hB, nullptr, N);
    gather64_kernel<<<nbW, 256, 0, stream>>>(hB, rowptr, csr, dinv, agg16, N);
    mm64_kernel<false><<<nbG, 256, 0, stream>>>(agg16, W3, b3, hA, nullptr, N);
    gather64_kernel<<<nbW, 256, 0, stream>>>(hA, rowptr, csr, dinv, agg16, N);
    mm64_kernel<true><<<nbG, 256, 0, stream>>>(agg16, W4, b4, nullptr, blkmax, N);

    // two-stage blkmax reduction + final dot
    pool_part_kernel<<<64, 256, 0, stream>>>(blkmax, nbG, part);
    pool_out_kernel<<<1, 256, 0, stream>>>(part, Wr, br, out);
}

// Round 14
// 277.140 us; speedup vs baseline: 1.2678x; 1.0004x over previous
//
#include <hip/hip_runtime.h>
#include <hip/hip_fp16.h>
#include <math.h>

// GCN forward, reordered per-layer as x_{l} = relu((A x_{l-1}) @ W_l + b_l)
// (valid since A(xW) == (Ax)W). Then global max pool -> dot Wr.
//
// Split gather/mm per layer. h AND agg fp16; CSR packed int2{src, norm_bits}.
// gather64 edge loop unrolled 2x with paired loads: 16 random rows in flight
// per wave (deg~Poisson(8) -> one round-trip for ~95% of nodes).
// Layer 4's mm fuses max-pool -> blkmax rows (no atomics), two-stage reduce.

__global__ void init_kernel(int* counts, int N) {
    int i = blockIdx.x * blockDim.x + threadIdx.x;
    if (i < N) counts[i] = 0;
}

// pass 1: reserve a slot per edge within its dst row. 800k atomics total.
__global__ void count_slot_kernel(const int* __restrict__ dst, int* counts, int* eslot, int E) {
    int e = blockIdx.x * blockDim.x + threadIdx.x;
    if (e >= E) return;
    eslot[e] = atomicAdd(&counts[dst[e]], 1);
}

// ---- two-level exclusive scan of counts -> rowptr ----
__global__ void scan1_kernel(const int* __restrict__ counts, int* bsums, int N) {
    __shared__ int s[256];
    int t = threadIdx.x, i = blockIdx.x * 256 + t;
    s[t] = (i < N) ? counts[i] : 0;
    __syncthreads();
    for (int o = 128; o > 0; o >>= 1) {
        if (t < o) s[t] += s[t + o];
        __syncthreads();
    }
    if (t == 0) bsums[blockIdx.x] = s[0];
}

__global__ void scan2_kernel(int* bsums, int nb) {  // nb <= 512
    __shared__ int s[512];
    int t = threadIdx.x;
    int v = (t < nb) ? bsums[t] : 0;
    s[t] = v; __syncthreads();
    for (int o = 1; o < 512; o <<= 1) {
        int x = (t >= o) ? s[t - o] : 0;
        __syncthreads();
        s[t] += x;
        __syncthreads();
    }
    if (t < nb) bsums[t] = s[t] - v;  // exclusive
}

__global__ void scan3_kernel(const int* __restrict__ counts, const int* __restrict__ bsums,
                             int* rowptr, int N) {
    __shared__ int s[256];
    int t = threadIdx.x, i = blockIdx.x * 256 + t;
    int v = (i < N) ? counts[i] : 0;
    s[t] = v; __syncthreads();
    for (int o = 1; o < 256; o <<= 1) {
        int x = (t >= o) ? s[t - o] : 0;
        __syncthreads();
        s[t] += x;
        __syncthreads();
    }
    if (i <= N) rowptr[i] = bsums[blockIdx.x] + s[t] - v;  // rowptr[N] == E
}

// pass 2: atomic-free CSR fill using reserved slots. Packed int2{src, w_bits}.
__global__ void fill2_kernel(const int* __restrict__ src, const int* __restrict__ dst,
                             const float* __restrict__ w, const int* __restrict__ rowptr,
                             const int* __restrict__ eslot, int2* __restrict__ csr, int E) {
    int e = blockIdx.x * blockDim.x + threadIdx.x;
    if (e >= E) return;
    int p = rowptr[dst[e]] + eslot[e];
    csr[p] = make_int2(src[e], __float_as_int(w[e]));
}

// deg[i] = 1 + sum(w row) (self loop), dinv = 1/sqrt(deg). Coalesced, no atomics.
__global__ void degdinv_kernel(const int2* __restrict__ csr, const int* __restrict__ rowptr,
                               float* dinv, int N) {
    int i = blockIdx.x * blockDim.x + threadIdx.x;
    if (i >= N) return;
    float d = 1.0f;
    int jb = rowptr[i], je = rowptr[i + 1];
    for (int j = jb; j < je; ++j) d += __int_as_float(csr[j].y);
    dinv[i] = 1.0f / sqrtf(d);
}

// in-place: csr[j].y <- dinv[src] * w * dinv[i]
__global__ void norm_kernel(const int* __restrict__ rowptr, const float* __restrict__ dinv,
                            int2* __restrict__ csr, int N) {
    int i = blockIdx.x * blockDim.x + threadIdx.x;
    if (i >= N) return;
    float dn = dinv[i];
    int jb = rowptr[i], je = rowptr[i + 1];
    for (int j = jb; j < je; ++j) {
        int2 ed = csr[j];
        csr[j] = make_int2(ed.x, __float_as_int(dinv[ed.x] * __int_as_float(ed.y) * dn));
    }
}

// 6-wide gather, thread per node; edge loop unrolled 2x (independent row loads).
__global__ void gather6_kernel(const float* __restrict__ x, const int* __restrict__ rowptr,
                               const int2* __restrict__ csr,
                               const float* __restrict__ dinv, float* __restrict__ g, int N) {
    int i = blockIdx.x * blockDim.x + threadIdx.x;
    if (i >= N) return;
    float dn = dinv[i];
    float sc = dn * dn;
    float acc[6];
    {
        const float2* xr = (const float2*)(x + (size_t)i * 6);
        float2 a = xr[0], bv = xr[1], c = xr[2];
        acc[0] = sc * a.x; acc[1] = sc * a.y; acc[2] = sc * bv.x;
        acc[3] = sc * bv.y; acc[4] = sc * c.x; acc[5] = sc * c.y;
    }
    int jb = rowptr[i], je = rowptr[i + 1];
    int j = jb;
    for (; j + 1 < je; j += 2) {
        int2 e0 = csr[j], e1 = csr[j + 1];
        float n0 = __int_as_float(e0.y), n1 = __int_as_float(e1.y);
        const float2* x0 = (const float2*)(x + (size_t)e0.x * 6);
        const float2* x1 = (const float2*)(x + (size_t)e1.x * 6);
        float2 a0 = x0[0], b0 = x0[1], c0 = x0[2];
        float2 a1 = x1[0], b1 = x1[1], c1 = x1[2];
        acc[0] = fmaf(n0, a0.x, acc[0]); acc[1] = fmaf(n0, a0.y, acc[1]);
        acc[2] = fmaf(n0, b0.x, acc[2]); acc[3] = fmaf(n0, b0.y, acc[3]);
        acc[4] = fmaf(n0, c0.x, acc[4]); acc[5] = fmaf(n0, c0.y, acc[5]);
        acc[0] = fmaf(n1, a1.x, acc[0]); acc[1] = fmaf(n1, a1.y, acc[1]);
        acc[2] = fmaf(n1, b1.x, acc[2]); acc[3] = fmaf(n1, b1.y, acc[3]);
        acc[4] = fmaf(n1, c1.x, acc[4]); acc[5] = fmaf(n1, c1.y, acc[5]);
    }
    if (j < je) {
        int2 e0 = csr[j];
        float n0 = __int_as_float(e0.y);
        const float2* x0 = (const float2*)(x + (size_t)e0.x * 6);
        float2 a0 = x0[0], b0 = x0[1], c0 = x0[2];
        acc[0] = fmaf(n0, a0.x, acc[0]); acc[1] = fmaf(n0, a0.y, acc[1]);
        acc[2] = fmaf(n0, b0.x, acc[2]); acc[3] = fmaf(n0, b0.y, acc[3]);
        acc[4] = fmaf(n0, c0.x, acc[4]); acc[5] = fmaf(n0, c0.y, acc[5]);
    }
#pragma unroll
    for (int f = 0; f < 6; ++f) g[(size_t)i * 6 + f] = acc[f];
}

// 64-wide gather over fp16 h: wave per node, 8 edge-groups x 8 lanes, uint4
// per lane; edge loop unrolled 2x -> 16 random rows in flight per wave.
// fp32 accumulate; 3-step shfl reduce; group 0 writes fp16 agg row.
__global__ void gather64_kernel(const __half* __restrict__ h, const int* __restrict__ rowptr,
                                const int2* __restrict__ csr,
                                const float* __restrict__ dinv, __half* __restrict__ agg, int N) {
    int wid = blockIdx.x * (blockDim.x >> 6) + (threadIdx.x >> 6);
    if (wid >= N) return;
    int lane = threadIdx.x & 63;
    int g = lane >> 3;      // edge group 0..7
    int l8 = lane & 7;      // 16B slot within 128B row
    float4 accA = {0.f, 0.f, 0.f, 0.f};
    float4 accB = {0.f, 0.f, 0.f, 0.f};
    if (g == 0) {
        float dn = dinv[wid];
        float sc = dn * dn;
        uint4 r = ((const uint4*)(h + (size_t)wid * 64))[l8];
        __half2 p0 = *(__half2*)&r.x, p1 = *(__half2*)&r.y;
        __half2 p2 = *(__half2*)&r.z, p3 = *(__half2*)&r.w;
        float2 f0 = __half22float2(p0), f1 = __half22float2(p1);
        float2 f2 = __half22float2(p2), f3 = __half22float2(p3);
        accA.x = sc * f0.x; accA.y = sc * f0.y; accA.z = sc * f1.x; accA.w = sc * f1.y;
        accB.x = sc * f2.x; accB.y = sc * f2.y; accB.z = sc * f3.x; accB.w = sc * f3.y;
    }
    int jb = rowptr[wid], je = rowptr[wid + 1];
    int j = jb + g;
#define G64_FMA(RR, NM) { \
        __half2 p0 = *(__half2*)&RR.x, p1 = *(__half2*)&RR.y; \
        __half2 p2 = *(__half2*)&RR.z, p3 = *(__half2*)&RR.w; \
        float2 f0 = __half22float2(p0), f1 = __half22float2(p1); \
        float2 f2 = __half22float2(p2), f3 = __half22float2(p3); \
        accA.x = fmaf(NM, f0.x, accA.x); accA.y = fmaf(NM, f0.y, accA.y); \
        accA.z = fmaf(NM, f1.x, accA.z); accA.w = fmaf(NM, f1.y, accA.w); \
        accB.x = fmaf(NM, f2.x, accB.x); accB.y = fmaf(NM, f2.y, accB.y); \
        accB.z = fmaf(NM, f3.x, accB.z); accB.w = fmaf(NM, f3.y, accB.w); }
    for (; j + 8 < je; j += 16) {
        int2 e0 = csr[j];
        int2 e1 = csr[j + 8];
        uint4 r0 = ((const uint4*)(h + (size_t)e0.x * 64))[l8];
        uint4 r1 = ((const uint4*)(h + (size_t)e1.x * 64))[l8];
        float n0 = __int_as_float(e0.y), n1 = __int_as_float(e1.y);
        G64_FMA(r0, n0)
        G64_FMA(r1, n1)
    }
    if (j < je) {
        int2 e0 = csr[j];
        uint4 r0 = ((const uint4*)(h + (size_t)e0.x * 64))[l8];
        float n0 = __int_as_float(e0.y);
        G64_FMA(r0, n0)
    }
#undef G64_FMA
#pragma unroll
    for (int o = 8; o <= 32; o <<= 1) {
        accA.x += __shfl_xor(accA.x, o);
        accA.y += __shfl_xor(accA.y, o);
        accA.z += __shfl_xor(accA.z, o);
        accA.w += __shfl_xor(accA.w, o);
        accB.x += __shfl_xor(accB.x, o);
        accB.y += __shfl_xor(accB.y, o);
        accB.z += __shfl_xor(accB.z, o);
        accB.w += __shfl_xor(accB.w, o);
    }
    if (g == 0) {
        __half2 q0 = __floats2half2_rn(accA.x, accA.y);
        __half2 q1 = __floats2half2_rn(accA.z, accA.w);
        __half2 q2 = __floats2half2_rn(accB.x, accB.y);
        __half2 q3 = __floats2half2_rn(accB.z, accB.w);
        uint4 pk;
        pk.x = *(unsigned int*)&q0; pk.y = *(unsigned int*)&q1;
        pk.z = *(unsigned int*)&q2; pk.w = *(unsigned int*)&q3;
        ((uint4*)(agg + (size_t)wid * 64))[l8] = pk;
    }
}

// h = relu(xin @ W + b), 64->64 fp16-in fp32-math. LDS-tiled vector GEMM;
// thread (ty,tx) = 4 nodes x 4 ch. FUSE_POOL: per-block LDS max-reduce ->
// one coalesced blkmax row write (NO atomics).
template<bool FUSE_POOL>
__global__ void __launch_bounds__(256)
__attribute__((amdgpu_waves_per_eu(2, 4)))
mm64_kernel(const __half* __restrict__ xin, const float* __restrict__ W,
            const float* __restrict__ b, __half* __restrict__ h_out,
            float* blkmax, int N) {
    __shared__ float xl[64 * 68];
    __shared__ float Wt[64 * 68];
    const int tid = threadIdx.x;
    const long nb = (long)blockIdx.x * 64;

#pragma unroll
    for (int r = 0; r < 4; ++r) {
        int q = tid + 256 * r;          // float4 index 0..1023
        int row = q >> 4, c4 = q & 15;
        ((float4*)&Wt[row * 68 + c4 * 4])[0] = ((const float4*)W)[q];
    }
#pragma unroll
    for (int r = 0; r < 2; ++r) {
        int q = tid + 256 * r;          // uint4 index 0..511 (64 rows x 8)
        int row = q >> 3, u4 = q & 7;
        long n = nb + row;
        float4 vA = {0.f, 0.f, 0.f, 0.f}, vB = {0.f, 0.f, 0.f, 0.f};
        if (n < N) {
            uint4 rr = ((const uint4*)(xin + n * 64))[u4];
            __half2 p0 = *(__half2*)&rr.x, p1 = *(__half2*)&rr.y;
            __half2 p2 = *(__half2*)&rr.z, p3 = *(__half2*)&rr.w;
            float2 f0 = __half22float2(p0), f1 = __half22float2(p1);
            float2 f2 = __half22float2(p2), f3 = __half22float2(p3);
            vA.x = f0.x; vA.y = f0.y; vA.z = f1.x; vA.w = f1.y;
            vB.x = f2.x; vB.y = f2.y; vB.z = f3.x; vB.w = f3.y;
        }
        float* dstp = &xl[row * 68 + u4 * 8];
        ((float4*)dstp)[0] = vA;
        ((float4*)dstp)[1] = vB;
    }
    __syncthreads();

    const int tx = tid & 15;   // channel group: ch = tx*4..+3
    const int ty = tid >> 4;   // node group:    n = ty*4..+3

    float4 acc0 = {0,0,0,0}, acc1 = {0,0,0,0}, acc2 = {0,0,0,0}, acc3 = {0,0,0,0};
#pragma unroll 4
    for (int kc = 0; kc < 16; ++kc) {
        float4 w0 = *(const float4*)&Wt[(kc * 4 + 0) * 68 + tx * 4];
        float4 w1 = *(const float4*)&Wt[(kc * 4 + 1) * 68 + tx * 4];
        float4 w2 = *(const float4*)&Wt[(kc * 4 + 2) * 68 + tx * 4];
        float4 w3 = *(const float4*)&Wt[(kc * 4 + 3) * 68 + tx * 4];
        float4 x0 = *(const float4*)&xl[(ty * 4 + 0) * 68 + kc * 4];
        float4 x1 = *(const float4*)&xl[(ty * 4 + 1) * 68 + kc * 4];
        float4 x2 = *(const float4*)&xl[(ty * 4 + 2) * 68 + kc * 4];
        float4 x3 = *(const float4*)&xl[(ty * 4 + 3) * 68 + kc * 4];
#define MMSTEP(A, X) \
        A.x = fmaf(X.x, w0.x, A.x); A.y = fmaf(X.x, w0.y, A.y); A.z = fmaf(X.x, w0.z, A.z); A.w = fmaf(X.x, w0.w, A.w); \
        A.x = fmaf(X.y, w1.x, A.x); A.y = fmaf(X.y, w1.y, A.y); A.z = fmaf(X.y, w1.z, A.z); A.w = fmaf(X.y, w1.w, A.w); \
        A.x = fmaf(X.z, w2.x, A.x); A.y = fmaf(X.z, w2.y, A.y); A.z = fmaf(X.z, w2.z, A.z); A.w = fmaf(X.z, w2.w, A.w); \
        A.x = fmaf(X.w, w3.x, A.x); A.y = fmaf(X.w, w3.y, A.y); A.z = fmaf(X.w, w3.z, A.z); A.w = fmaf(X.w, w3.w, A.w);
        MMSTEP(acc0, x0) MMSTEP(acc1, x1) MMSTEP(acc2, x2) MMSTEP(acc3, x3)
#undef MMSTEP
    }

    float4 vb = ((const float4*)b)[tx];
    if (!FUSE_POOL) {
#define MMOUT(A, I) { \
        long n = nb + ty * 4 + I; \
        if (n < N) { \
            float o0 = fmaxf(A.x + vb.x, 0.f), o1 = fmaxf(A.y + vb.y, 0.f); \
            float o2 = fmaxf(A.z + vb.z, 0.f), o3 = fmaxf(A.w + vb.w, 0.f); \
            __half2 p0 = __floats2half2_rn(o0, o1), p1 = __floats2half2_rn(o2, o3); \
            uint2 pk; pk.x = *(unsigned int*)&p0; pk.y = *(unsigned int*)&p1; \
            ((uint2*)(h_out + n * 64))[tx] = pk; \
        } }
        MMOUT(acc0, 0) MMOUT(acc1, 1) MMOUT(acc2, 2) MMOUT(acc3, 3)
#undef MMOUT
    } else {
        float4 m = {0.f, 0.f, 0.f, 0.f};
#define MMMAX(A, I) { \
        long n = nb + ty * 4 + I; \
        if (n < N) { \
            m.x = fmaxf(m.x, A.x + vb.x); m.y = fmaxf(m.y, A.y + vb.y); \
            m.z = fmaxf(m.z, A.z + vb.z); m.w = fmaxf(m.w, A.w + vb.w); \
        } }
        MMMAX(acc0, 0) MMMAX(acc1, 1) MMMAX(acc2, 2) MMMAX(acc3, 3)
#undef MMMAX
        __syncthreads();                        // done reading xl
        ((float4*)xl)[ty * 16 + tx] = m;        // xl as [16 ty][16 tx] float4
        __syncthreads();
#pragma unroll
        for (int off = 8; off > 0; off >>= 1) {
            if (ty < off) {
                float4 a = ((float4*)xl)[ty * 16 + tx];
                float4 c = ((float4*)xl)[(ty + off) * 16 + tx];
                a.x = fmaxf(a.x, c.x); a.y = fmaxf(a.y, c.y);
                a.z = fmaxf(a.z, c.z); a.w = fmaxf(a.w, c.w);
                ((float4*)xl)[ty * 16 + tx] = a;
            }
            __syncthreads();
        }
        if (ty == 0)   // one coalesced 256B row store, zero atomics
            ((float4*)(blkmax + (size_t)blockIdx.x * 64))[tx] = ((float4*)xl)[tx];
    }
}

// h[n*64+c] = relu(xin[n] @ W[:,c] + b[c]) -> fp16, 6->64. Thread per (node,ch).
__global__ void __launch_bounds__(256)
mm6_kernel(const float* __restrict__ xin, const float* __restrict__ W,
           const float* __restrict__ b, __half* __restrict__ h, int N) {
    long idx = (long)blockIdx.x * blockDim.x + threadIdx.x;  // node*64 + ch
    if (idx >= (long)N * 64) return;
    long n = idx >> 6;
    int c = (int)(idx & 63);
    const float* xr = xin + n * 6;
    float a = b[c];
    a = fmaf(xr[0], W[0 * 64 + c], a);
    a = fmaf(xr[1], W[1 * 64 + c], a);
    a = fmaf(xr[2], W[2 * 64 + c], a);
    a = fmaf(xr[3], W[3 * 64 + c], a);
    a = fmaf(xr[4], W[4 * 64 + c], a);
    a = fmaf(xr[5], W[5 * 64 + c], a);
    h[idx] = __float2half(fmaxf(a, 0.0f));
}

// Stage 1: 64 blocks; block r max-reduces rows r, r+64, ... of blkmax
// into part[r][64]. Loads are independent -> latency overlapped.
__global__ void pool_part_kernel(const float* __restrict__ blkmax, int nrows,
                                 float* __restrict__ part) {
    int tid = threadIdx.x;
    int c = tid & 63, q = tid >> 6;          // q = 0..3
    int r0 = blockIdx.x + q * 64;            // rows strided by 256 per thread
    float m = 0.0f;
    for (int r = r0; r < nrows; r += 256)
        m = fmaxf(m, blkmax[(size_t)r * 64 + c]);
    __shared__ float red[256];
    red[tid] = m;
    __syncthreads();
    if (tid < 64) {
        m = fmaxf(fmaxf(red[tid], red[tid + 64]), fmaxf(red[tid + 128], red[tid + 192]));
        part[(size_t)blockIdx.x * 64 + tid] = m;
    }
}

// Stage 2: single block reduces part[64][64] (16KB, L2-hot) -> out scalar.
__global__ void pool_out_kernel(const float* __restrict__ part,
                                const float* __restrict__ Wr, const float* __restrict__ br,
                                float* out) {
    __shared__ float red[256];
    int tid = threadIdx.x;
    int c = tid & 63, q = tid >> 6;
    float m = 0.0f;
    for (int r = q; r < 64; r += 4)
        m = fmaxf(m, part[(size_t)r * 64 + c]);
    red[tid] = m;
    __syncthreads();
    if (tid < 64) {
        m = fmaxf(fmaxf(red[tid], red[tid + 64]), fmaxf(red[tid + 128], red[tid + 192]));
        float v = m * Wr[tid];
#pragma unroll
        for (int o = 32; o > 0; o >>= 1) v += __shfl_xor(v, o);
        if (tid == 0) out[0] = v + br[0];
    }
}

extern "C" void kernel_launch(void* const* d_in, const int* in_sizes, int n_in,
                              void* d_out, int out_size, void* d_ws, size_t ws_size,
                              hipStream_t stream) {
    const float* vf = (const float*)d_in[0];
    const int* edges = (const int*)d_in[1];
    const float* w = (const float*)d_in[2];
    const float* W1 = (const float*)d_in[3];  const float* b1 = (const float*)d_in[4];
    const float* W2 = (const float*)d_in[5];  const float* b2 = (const float*)d_in[6];
    const float* W3 = (const float*)d_in[7];  const float* b3 = (const float*)d_in[8];
    const float* W4 = (const float*)d_in[9];  const float* b4 = (const float*)d_in[10];
    const float* Wr = (const float*)d_in[11]; const float* br = (const float*)d_in[12];
    float* out = (float*)d_out;

    const int FIN = 6;
    const int N = in_sizes[0] / FIN;   // 100000
    const int E = in_sizes[2];         // 800000
    const int* src = edges;
    const int* dst = edges + E;

    const int nbN = (N + 255) / 256;          // 391
    const int nbE = (E + 255) / 256;          // 3125
    const int nbW = (N + 3) / 4;              // gather64: wave-per-node
    const int nbG = (N + 63) / 64;            // mm64 blocks (64 nodes each)
    const int nbM6 = (int)(((long)N * 64 + 255) / 256);

    char* p = (char*)d_ws;
    float*  dinv    = (float*)p;   p += (size_t)N * 4;
    int*    rowptr  = (int*)p;     p += (size_t)(N + 1) * 4;
    int*    counts  = (int*)p;     p += (size_t)N * 4;
    int*    eslot   = (int*)p;     p += (size_t)E * 4;
    int2*   csr     = (int2*)p;    p += (size_t)E * 8;   // {src, w/norm bits}
    float*  g6      = (float*)p;   p += (size_t)N * 6 * 4;
    __half* hA      = (__half*)p;  p += (size_t)N * 64 * 2;
    __half* hB      = (__half*)p;  p += (size_t)N * 64 * 2;
    __half* agg16   = (__half*)p;  p += (size_t)N * 64 * 2;
    float*  blkmax  = (float*)p;   p += (size_t)nbG * 64 * 4;
    float*  part    = (float*)p;   p += (size_t)64 * 64 * 4;
    int*    bsums   = (int*)p;     p += 512 * 4;

    init_kernel<<<nbN, 256, 0, stream>>>(counts, N);
    count_slot_kernel<<<nbE, 256, 0, stream>>>(dst, counts, eslot, E);
    scan1_kernel<<<nbN, 256, 0, stream>>>(counts, bsums, N);
    scan2_kernel<<<1, 512, 0, stream>>>(bsums, nbN);
    scan3_kernel<<<nbN, 256, 0, stream>>>(counts, bsums, rowptr, N);
    fill2_kernel<<<nbE, 256, 0, stream>>>(src, dst, w, rowptr, eslot, csr, E);
    degdinv_kernel<<<nbN, 256, 0, stream>>>(csr, rowptr, dinv, N);
    norm_kernel<<<nbN, 256, 0, stream>>>(rowptr, dinv, csr, N);

    // layer 1: gather 6-wide, then mm 6->64 (+bias+relu) -> fp16 hA
    gather6_kernel<<<nbN, 256, 0, stream>>>(vf, rowptr, csr, dinv, g6, N);
    mm6_kernel<<<nbM6, 256, 0, stream>>>(g6, W1, b1, hA, N);
    // layers 2-4: gather (fp16 in/out) then GEMM; layer 4 fuses max-pool (no atomics)
    gather64_kernel<<<nbW, 256, 0, stream>>>(hA, rowptr, csr, dinv, agg16, N);
    mm64_kernel<false><<<nbG, 256, 0, stream>>>(agg16, W2, b2, hB, nullptr, N);
    gather64_kernel<<<nbW, 256, 0, stream>>>(hB, rowptr, csr, dinv, agg16, N);
    mm64_kernel<false><<<nbG, 256, 0, stream>>>(agg16, W3, b3, hA, nullptr, N);
    gather64_kernel<<<nbW, 256, 0, stream>>>(hA, rowptr, csr, dinv, agg16, N);
    mm64_kernel<true><<<nbG, 256, 0, stream>>>(agg16, W4, b4, nullptr, blkmax, N);

    // two-stage blkmax reduction + final dot
    pool_part_kernel<<<64, 256, 0, stream>>>(blkmax, nbG, part);
    pool_out_kernel<<<1, 256, 0, stream>>>(part, Wr, br, out);
}